// Round 11
// baseline (258.525 us; speedup 1.0000x reference)
//
// Self-attention (B=4,S=2048,D=1024) via W-fused GEMM pipeline.
#include <hip/hip_runtime.h>
#include <hip/hip_bf16.h>

typedef __attribute__((ext_vector_type(8))) __bf16 bf16x8;
typedef __attribute__((ext_vector_type(8))) short short8;
typedef __attribute__((ext_vector_type(4))) float f32x4;

#define BK 64
// Square TM x TM tiles (TM = 128 main, 64 for the tiny WT GEMM), BK=64,
// double-buffered 2-phase — the proven round-2/5/9 schedule. Round 6 measured
// BK=32 as a regression. LDS at TM=128: 64KB -> 2 blocks/CU.
//
// Bank swizzle (both-sides, rule #21/m173), BK=64 -> 8 16B slots/row:
// logical col16 c of row r stored at phys slot c ^ (r&7). Staging lane l
// (chunk row l>>3, slot l&7) fetches global col16 (l&7)^(l>>3); ds_read of
// logical slot q at row 16*i+lrow uses slot q^(lrow&7). Measured
// SQ_LDS_BANK_CONFLICT = 0 (rounds 2/5/9/10).
//
// Round-10 lesson: paired dual-B decode RAISED FETCH 32.8->41.0 MB (WT+VwT
// = 4MB thrash the 4MiB per-XCD L2) -> reverted to z-form dual.
// Round-10 counters: out-GEMM at ~368 TF vs dual 674 TF -> causal K-imbalance
// survives adjacent-id pairing -> mode 3 pairs at distance 256 instead
// (breadth-first co-residency hypothesis: CU c hosts blocks c and c+256).

__device__ inline unsigned short f2bf(float f) {  // RNE fp32->bf16
    union { float f; unsigned u; } v; v.f = f;
    unsigned r = (v.u + 0x7FFFu + ((v.u >> 16) & 1u)) >> 16;
    return (unsigned short)r;
}

// async global->LDS, 16B per lane. g: per-lane global addr; l: wave-uniform LDS base.
__device__ __forceinline__ void gld16(const void* g, void* l) {
    __builtin_amdgcn_global_load_lds(
        (const __attribute__((address_space(1))) unsigned int*)g,
        (__attribute__((address_space(3))) unsigned int*)l, 16, 0, 0);
}

// dtype probe: even ushorts of bf16 N(0,1) data have sane exponents (~100% in
// [0x60,0x88]); of fp32 data they are uniform mantissa bits (~16%).
__global__ void detect_dtype(const unsigned short* __restrict__ x, int* __restrict__ flag)
{
    const int tid = threadIdx.x;
    int cnt = 0;
    for (int i = tid; i < 1024; i += 256) {
        unsigned e = (x[2 * i] >> 7) & 0xFFu;
        cnt += (e >= 0x60u && e <= 0x88u) ? 1 : 0;
    }
    #pragma unroll
    for (int o = 32; o >= 1; o >>= 1) cnt += __shfl_xor(cnt, o, 64);
    __shared__ int red[4];
    if ((tid & 63) == 0) red[tid >> 6] = cnt;
    __syncthreads();
    if (tid == 0) {
        int t = red[0] + red[1] + red[2] + red[3];
        *flag = (t >= 512) ? 0 : 1;  // 0 = bf16 world, 1 = fp32 world
    }
}

// All input prep in ONE launch (flat grid, range-dispatched):
//   [0, nbX)            : Xb  = bf16(x)        straight copy, 8 elems/thread
//   [nbX, nbX+nbW)      : QwB = bf16(Qw)       straight copy
//   [nbX+nbW, nbX+2nbW) : KwB = bf16(Kw)       straight copy
//   [nbX+2nbW, +256)    : VwT = bf16(Vw)^T     64x64 LDS-tile transpose
__global__ __launch_bounds__(256)
void prep(const void* __restrict__ x, const void* __restrict__ Qw,
          const void* __restrict__ Kw, const void* __restrict__ Vw,
          unsigned short* __restrict__ Xb, unsigned short* __restrict__ QwB,
          unsigned short* __restrict__ KwB, unsigned short* __restrict__ VwT,
          long nX, long nW, int Dd, const int* __restrict__ dtf)
{
    const int dt = *dtf;
    const int bid = blockIdx.x;
    const int tid = threadIdx.x;
    const int nbX = (int)(nX >> 11);   // 2048 elems per copy block
    const int nbW = (int)(nW >> 11);
    __shared__ unsigned short tbuf[64][65];

    if (bid < nbX + 2 * nbW) {
        const void* s; unsigned short* d; long i;
        if (bid < nbX)            { s = x;  d = Xb;  i = ((long)bid << 11) + tid * 8; }
        else if (bid < nbX + nbW) { s = Qw; d = QwB; i = ((long)(bid - nbX) << 11) + tid * 8; }
        else                      { s = Kw; d = KwB; i = ((long)(bid - nbX - nbW) << 11) + tid * 8; }
        union { short8 v; unsigned short u[8]; } o;
        if (dt) {
            f32x4 a = *(const f32x4*)((const float*)s + i);
            f32x4 b = *(const f32x4*)((const float*)s + i + 4);
            #pragma unroll
            for (int j = 0; j < 4; j++) { o.u[j] = f2bf(a[j]); o.u[4 + j] = f2bf(b[j]); }
        } else {
            o.v = *(const short8*)((const short*)s + i);
        }
        *(short8*)(d + i) = o.v;
        return;
    }
    const int t64 = bid - (nbX + 2 * nbW);          // 0..(Dd/64)^2-1
    const int c0 = (t64 & 15) * 64, r0 = (t64 >> 4) * 64;
    #pragma unroll
    for (int it = 0; it < 16; it++) {
        int idx = it * 256 + tid;
        int r = idx >> 6, c = idx & 63;
        long e = (long)(r0 + r) * Dd + (c0 + c);
        tbuf[r][c] = dt ? f2bf(((const float*)Vw)[e]) : ((const unsigned short*)Vw)[e];
    }
    __syncthreads();
    #pragma unroll
    for (int it = 0; it < 16; it++) {
        int idx = it * 256 + tid;
        int r = idx >> 6, c = idx & 63;
        VwT[(long)(c0 + r) * Dd + (r0 + c)] = tbuf[c][r];
    }
}

// C = A @ Bt^T, all operands bf16. A [M][K] (lda), Bt [N][K] (ldb);
// offsets/strides in ELEMENTS. outKind: 0 bf16, 1 fp32, 2 external-dtype.
// mode 0: plain (XCD remap); z-form dual-B if Bt2 != null (blockIdx.z==1
//   switches to Bt2/C2 — r9-measured best form of the G+Vb merge).
// mode 1: enumerated causal tiles (triangle decode of blockIdx.x).
// mode 2: causal k-limit, adjacent-id heavy/light pairing (fallback path).
// mode 3: causal k-limit, DISTANCE-256 complementary pairing over a flat
//   512-block grid (Config A out-GEMM only; assumes 16mt x 8nt x 4z, q0=0).
//   Job list sorted kmax-desc: j = lin<256 ? lin : 767-lin; blocks lin and
//   lin+256 get jobs j and 511-j -> kmax sum = 128*17 = const. Balances
//   per-CU work if the scheduler fills CUs breadth-first (c, c+256).
template <int TM>
__global__ __launch_bounds__(256, 2)
void gemm_bt(const unsigned short* __restrict__ A, const unsigned short* __restrict__ Bt,
             void* __restrict__ Call, int K, int lda, int ldb, int ldc,
             long oA, long oB, long oC, long sA, long sB, long sC,
             float scale, int mode, int q0,
             const int* __restrict__ dtf, int outKind,
             const unsigned short* __restrict__ Bt2, void* __restrict__ C2)
{
    constexpr int NI = TM / 32;           // 16x16 frags per wave dim
    const int dt = *dtf;
    int zSel = blockIdx.z;
    if (mode != 3 && Bt2 && zSel) { Bt = Bt2; Call = C2; }   // z-form dual

    int mt, nt;
    if (mode == 3) {
        const int lin = blockIdx.x;                  // 512 blocks
        const int j = (lin < 256) ? lin : 767 - lin; // kmax-desc job index
        mt = 15 - (j >> 5);                          // j=0 -> heaviest (mt=15)
        zSel = (j >> 3) & 3;
        nt = j & 7;
    } else if (mode == 2) {
        const int nwg2 = gridDim.x * gridDim.y;
        const int h = blockIdx.y * gridDim.x + blockIdx.x;
        const int u = h >> 1;
        const int rank = (h & 1) ? (nwg2 - 1 - u) : u;   // 0 = heaviest
        mt = (gridDim.y - 1) - (rank / (int)gridDim.x);
        nt = rank % (int)gridDim.x;
    } else {
        // XCD-aware bijective remap (T1, m204 formula).
        const int nwg = gridDim.x * gridDim.y;
        int lin = blockIdx.y * gridDim.x + blockIdx.x;
        const int q = nwg >> 3, r = nwg & 7;
        const int xcd = lin & 7, idx = lin >> 3;
        lin = (xcd < r ? xcd * (q + 1) : r * (q + 1) + (xcd - r) * q) + idx;
        if (mode == 1) {  // decode linear id over the causal tile triangle
            int rem = lin, rr = 0, w = q0 / TM + 1;
            while (rem >= w) { rem -= w; rr++; w++; }
            mt = rr; nt = rem;
        } else { mt = lin / gridDim.x; nt = lin % gridDim.x; }
    }
    const long aBase = oA + (long)zSel * sA;
    const long bBase = oB + (long)zSel * sB;
    const long cBase = oC + (long)zSel * sC;
    const int m0 = mt * TM;
    const int n0 = nt * TM;
    int kmax = K;
    if (mode >= 2) kmax = min(K, q0 + m0 + TM);

    __shared__ __align__(16) short As[2][TM * BK];
    __shared__ __align__(16) short Bs[2][TM * BK];

    const int tid  = threadIdx.x;
    const int wave = tid >> 6;
    const int lane = tid & 63;
    const int wm = (wave >> 1) * (TM / 2);
    const int wn = (wave & 1) * (TM / 2);
    const int lrow = lane & 15;
    const int quad = lane >> 4;

    // Staging: per wave TM/4 rows of A and of B per K-step, in 8-row/1KB gld16
    // chunks. lane l -> chunk row l>>3, pre-swizzled global col16 (l&7)^(l>>3).
    const int sRow = lane >> 3;
    const int sCol = ((lane & 7) ^ sRow) * 8;  // elements
    const long gA = aBase + (long)(m0 + wave * (TM / 4) + sRow) * lda + sCol;
    const long gB = bBase + (long)(n0 + wave * (TM / 4) + sRow) * ldb + sCol;

    auto stage = [&](int buf, int k0) {
        short* dA = &As[buf][wave * (TM / 4) * BK];
        short* dB = &Bs[buf][wave * (TM / 4) * BK];
        const unsigned short* pA = A + gA + k0;
        const unsigned short* pB = Bt + gB + k0;
        #pragma unroll
        for (int c = 0; c < TM / 32; c++) {
            gld16(pA + (long)(c * 8) * lda, dA + c * 8 * BK);
            gld16(pB + (long)(c * 8) * ldb, dB + c * 8 * BK);
        }
    };

    f32x4 acc[NI][NI];
    #pragma unroll
    for (int i = 0; i < NI; i++)
        #pragma unroll
        for (int j = 0; j < NI; j++) {
            f32x4 zero = {0.f, 0.f, 0.f, 0.f};
            acc[i][j] = zero;
        }

    // ds_read physical col16 slots for the two K-halves (lane-constant:
    // row = wm + i*16 + lrow, and wm/i*16 are multiples of 8 -> row&7 == lrow&7).
    const int rq  = lrow & 7;
    const int pc0 = (quad ^ rq) * 8;
    const int pc1 = ((quad + 4) ^ rq) * 8;

    stage(0, 0);
    __syncthreads();    // vmcnt(0) drained before barrier -> tile 0 ready
    int cur = 0;

    for (int k0 = 0; k0 < kmax; k0 += BK) {
        const int kn = k0 + BK;
        if (kn < kmax) stage(cur ^ 1, kn);   // prefetch in flight during compute

        const short* rA = &As[cur][0];
        const short* rB = &Bs[cur][0];
        bf16x8 af[NI], bfr[NI];
        #pragma unroll
        for (int i = 0; i < NI; i++) {
            af[i]  = *(const bf16x8*)&rA[(wm + i * 16 + lrow) * BK + pc0];
            bfr[i] = *(const bf16x8*)&rB[(wn + i * 16 + lrow) * BK + pc0];
        }
        #pragma unroll
        for (int i = 0; i < NI; i++)
            #pragma unroll
            for (int j = 0; j < NI; j++)
                acc[i][j] = __builtin_amdgcn_mfma_f32_16x16x32_bf16(af[i], bfr[j], acc[i][j], 0, 0, 0);
        #pragma unroll
        for (int i = 0; i < NI; i++) {
            af[i]  = *(const bf16x8*)&rA[(wm + i * 16 + lrow) * BK + pc1];
            bfr[i] = *(const bf16x8*)&rB[(wn + i * 16 + lrow) * BK + pc1];
        }
        #pragma unroll
        for (int i = 0; i < NI; i++)
            #pragma unroll
            for (int j = 0; j < NI; j++)
                acc[i][j] = __builtin_amdgcn_mfma_f32_16x16x32_bf16(af[i], bfr[j], acc[i][j], 0, 0, 0);

        __syncthreads();   // drains prefetch (vmcnt) + readers (lgkm); swap
        cur ^= 1;
    }

    const int oF32 = (outKind == 1) | ((outKind == 2) & dt);
    // C/D layout (m89-verified): col = lane&15, row = quad*4 + reg
    #pragma unroll
    for (int i = 0; i < NI; i++) {
        const int mr = m0 + wm + i * 16 + quad * 4;
        #pragma unroll
        for (int j = 0; j < NI; j++) {
            const int nc = n0 + wn + j * 16 + lrow;
            #pragma unroll
            for (int r = 0; r < 4; r++) {
                const long ofs = cBase + (long)(mr + r) * ldc + nc;
                const float v = acc[i][j][r] * scale;
                if (oF32) ((float*)Call)[ofs] = v;
                else      ((unsigned short*)Call)[ofs] = f2bf(v);
            }
        }
    }
}

// One-pass cast/transpose: src [R][C] (dtype per flag if srcExt).
// dT (optional): bf16 [C][R] transposed. dC (optional): bf16 [R][C] straight copy.
__global__ __launch_bounds__(256)
void xpose_cast(const void* __restrict__ src, unsigned short* __restrict__ dT,
                unsigned short* __restrict__ dC, int R, int C,
                long oS, long sS, long sDT, long sDC,
                const int* __restrict__ dtf, int srcExt)
{
    const int dt = srcExt ? *dtf : 0;
    const int b = blockIdx.z;
    const long sb = oS + (long)b * sS;
    __shared__ unsigned short t[64][65];
    const int c0 = blockIdx.x * 64, r0 = blockIdx.y * 64;
    const int tid = threadIdx.x;
    #pragma unroll
    for (int it = 0; it < 16; it++) {
        int idx = it * 256 + tid;
        int r = idx >> 6, c = idx & 63;
        long e = sb + (long)(r0 + r) * C + (c0 + c);
        unsigned short v = dt ? f2bf(((const float*)src)[e]) : ((const unsigned short*)src)[e];
        t[r][c] = v;
        if (dC) dC[(long)b * sDC + (long)(r0 + r) * C + (c0 + c)] = v;
    }
    if (!dT) return;
    __syncthreads();
    #pragma unroll
    for (int it = 0; it < 16; it++) {
        int idx = it * 256 + tid;
        int r = idx >> 6, c = idx & 63;
        dT[(long)b * sDT + (long)(c0 + r) * R + (r0 + c)] = t[c][r];
    }
}

// Sc chunk fp32 [ZB][CH][S]; row (global q0+r) softmaxed, written back IN PLACE
// as bf16 P in the first half of its own fp32 row (P lda = 2S). Vectorized
// (G13): 8 contiguous elems/thread, f32x4 x2 loads + short8 store. Store guard
// is uniform over the 8-group (limit % 128 == 0, j0 % 8 == 0). Elements >=
// limit are never read by the out-GEMM; [n, limit) masked to 0 before pack.
// Beyond-n loads may hit stale ws bytes (finite or NaN) — masked to -1e30
// before any arithmetic, so NaN never propagates.
__global__ __launch_bounds__(256)
void softmax_causal(float* __restrict__ Sc, int S, int CH, int q0)
{
    const int r = blockIdx.x, z = blockIdx.y;
    float* srow = Sc + ((long)z * CH + r) * S;
    unsigned short* prow = (unsigned short*)srow;
    const int n = q0 + r + 1;
    const int limit = q0 + (r & ~127) + 128;   // tile-aligned causal bound
    const int tid = threadIdx.x;
    const int lane = tid & 63, wave = tid >> 6;
    const int j0 = tid * 8;
    __shared__ float red[4];

    float v[8];
    {
        f32x4 a = *(const f32x4*)(srow + j0);
        f32x4 b = *(const f32x4*)(srow + j0 + 4);
        #pragma unroll
        for (int c = 0; c < 4; c++) { v[c] = a[c]; v[4 + c] = b[c]; }
    }
    float lm = -1e30f;
    #pragma unroll
    for (int c = 0; c < 8; c++) {
        v[c] = (j0 + c < n) ? v[c] : -1e30f;
        lm = fmaxf(lm, v[c]);
    }
    #pragma unroll
    for (int o = 32; o >= 1; o >>= 1) lm = fmaxf(lm, __shfl_xor(lm, o, 64));
    if (lane == 0) red[wave] = lm;
    __syncthreads();
    const float m = fmaxf(fmaxf(red[0], red[1]), fmaxf(red[2], red[3]));
    __syncthreads();

    float ev[8];
    float ls = 0.f;
    #pragma unroll
    for (int c = 0; c < 8; c++) {
        float e = (j0 + c < n) ? __expf(v[c] - m) : 0.f;
        ev[c] = e;
        ls += e;
    }
    #pragma unroll
    for (int o = 32; o >= 1; o >>= 1) ls += __shfl_xor(ls, o, 64);
    if (lane == 0) red[wave] = ls;
    __syncthreads();   // all fp32 reads done before aliasing bf16 writes
    const float inv = 1.0f / (red[0] + red[1] + red[2] + red[3]);

    if (j0 < limit) {
        union { short8 s; unsigned short u[8]; } o;
        #pragma unroll
        for (int c = 0; c < 8; c++) o.u[c] = f2bf(ev[c] * inv);
        *(short8*)(prow + j0) = o.s;
    }
}

__global__ __launch_bounds__(256)
void fill_zero(void* o, long n, const int* dtf)
{
    long i = (long)blockIdx.x * 256 + threadIdx.x;
    if (i < n) {
        if (*dtf) ((float*)o)[i] = 0.f;
        else ((unsigned short*)o)[i] = 0;
    }
}

extern "C" void kernel_launch(void* const* d_in, const int* in_sizes, int n_in,
                              void* d_out, int out_size, void* d_ws, size_t ws_size,
                              hipStream_t stream)
{
    const int B = 4, S = 2048, D = 1024;
    const void* x  = d_in[0];
    const void* Qw = d_in[1];
    const void* Kw = d_in[2];
    const void* Vw = d_in[3];
    (void)in_sizes; (void)n_in; (void)out_size;

    // Algebra: scores = X (Qw Kw^T) X^T / 32 ; out = P (X Vw).
    //   prep: Xb/QwB/KwB/VwT in one launch
    //   WT = Kw @ Qw^T / 32        (256 blocks)
    //   G  = Xb @ WT^T -> Buf  \  z-form dual launch (1024 blocks)
    //   Vb = Xb @ VwT^T -> VbS /
    //   Sc = G @ Xb^T  (causal) -> softmax in place -> P
    //   out = P @ Vb^T (causal mode 3, distance-256 balanced) -> d_out
    int* dtf = (int*)d_ws;
    char* p = (char*)d_ws + 4096;
    const size_t MB = (size_t)1 << 20;
    const unsigned short* nullB = nullptr;

    detect_dtype<<<1, 256, 0, stream>>>((const unsigned short*)x, dtf);

    const long nOut = (long)B * S * D;
    const long nX = (long)B * S * D;
    const long nW = (long)D * D;
    const int prepBlocks = (int)(nX >> 11) + 2 * (int)(nW >> 11) + (D / 64) * (D / 64);

    // ---- Config A: single chunk with buffer aliasing.
    // ws: dtf | QwB 2MB | KwB 2MB | Xb 16MB (later VbT) | Buf 16MB (G) |
    //     Sc fp32 64MB (WT bf16 in first 2MB, VwT in next 2MB — both consumed
    //     by the dual GEMM before the Sc GEMM overwrites them).
    // Vb is staged through d_out (dead until the final causal GEMM).
    const size_t needA = 4096 + 36 * MB + (size_t)B * S * S * 4;
    if (ws_size >= needA) {
        unsigned short* QwB = (unsigned short*)p;
        unsigned short* KwB = (unsigned short*)(p + 2 * MB);
        unsigned short* Xb  = (unsigned short*)(p + 4 * MB);
        unsigned short* Buf = (unsigned short*)(p + 20 * MB);
        float* Sc = (float*)(p + 36 * MB);
        unsigned short* WT  = (unsigned short*)Sc;            // Sc head
        unsigned short* VwT = (unsigned short*)((char*)Sc + 2 * MB);
        unsigned short* VbT = Xb;                             // Xb dead after Sc
        unsigned short* VbS = (unsigned short*)d_out;         // Vb scratch

        prep<<<dim3(prepBlocks), 256, 0, stream>>>(
            x, Qw, Kw, Vw, Xb, QwB, KwB, VwT, nX, nW, D, dtf);
        // WT = Kw @ Qw^T / 32   [256 blocks]
        gemm_bt<64><<<dim3(16, 16, 1), 256, 0, stream>>>(
            KwB, QwB, WT, D, D, D, D, 0L, 0L, 0L, 0L, 0L, 0L,
            0.03125f, 0, 0, dtf, 0, nullB, nullptr);
        // G = Xb @ WT^T -> Buf || Vb = Xb @ VwT^T -> VbS  [z-form, 1024 blocks]
        gemm_bt<128><<<dim3(8, 64, 2), 256, 0, stream>>>(
            Xb, WT, Buf, D, D, D, D, 0L, 0L, 0L, 0L, 0L, 0L,
            1.0f, 0, 0, dtf, 0, VwT, VbS);
        // Sc = G @ Xb^T  (enumerated causal tiles)   [544 blocks]
        gemm_bt<128><<<dim3(136, 1, 4), 256, 0, stream>>>(
            Buf, Xb, (void*)Sc, D, D, D, S,
            0L, 0L, 0L, (long)S * D, (long)S * D, (long)S * S,
            1.0f, 1, 0, dtf, 1, nullB, nullptr);
        softmax_causal<<<dim3(S, 4), 256, 0, stream>>>(Sc, S, S, 0);
        // VbT[b][d][s] = Vb[b][s][d]  (overwrites Xb — dead only now)
        xpose_cast<<<dim3(16, 32, 4), 256, 0, stream>>>(
            VbS, VbT, nullptr, S, D, 0L, (long)S * D, (long)D * S, 0L, dtf, 0);
        // out = P @ Vb^T (mode 3: flat 512 grid, distance-256 balance) -> d_out
        gemm_bt<128><<<dim3(512, 1, 1), 256, 0, stream>>>(
            (const unsigned short*)Sc, VbT, d_out, S, 2 * S, S, D,
            0L, 0L, 0L, (long)2 * S * S, (long)D * S, (long)S * D,
            1.0f, 3, 0, dtf, 2, nullB, nullptr);
        return;
    }

    // ---- Generic chunked fallback: fixed = 56MB + Sc chunk. Vb staged
    // through d_out (fully consumed into VbT before the loop writes d_out).
    const int cfgs[6][2] = {{4,1024},{2,1024},{1,1024},{1,512},{1,256},{1,128}};
    int ZB = 0, CH = 0;
    for (int i = 0; i < 6; i++) {
        size_t need = 4096 + 56 * MB + (size_t)cfgs[i][0] * cfgs[i][1] * S * 4;
        if (need <= ws_size) { ZB = cfgs[i][0]; CH = cfgs[i][1]; break; }
    }
    if (ZB == 0) {  // diagnostic zeros
        fill_zero<<<dim3((unsigned)((nOut + 255) / 256)), 256, 0, stream>>>(d_out, nOut, dtf);
        return;
    }

    unsigned short* QwB = (unsigned short*)p;
    unsigned short* KwB = (unsigned short*)(p + 2 * MB);
    unsigned short* WT  = (unsigned short*)(p + 4 * MB);
    unsigned short* VwT = (unsigned short*)(p + 6 * MB);
    unsigned short* Xb  = (unsigned short*)(p + 8 * MB);
    unsigned short* VbT = (unsigned short*)(p + 24 * MB);
    unsigned short* Buf = (unsigned short*)(p + 40 * MB);
    float* Sc = (float*)(p + 56 * MB);
    unsigned short* VbS = (unsigned short*)d_out;   // Vb scratch (dead pre-out)

    prep<<<dim3(prepBlocks), 256, 0, stream>>>(
        x, Qw, Kw, Vw, Xb, QwB, KwB, VwT, nX, nW, D, dtf);
    gemm_bt<64><<<dim3(16, 16, 1), 256, 0, stream>>>(
        KwB, QwB, WT, D, D, D, D, 0L, 0L, 0L, 0L, 0L, 0L,
        0.03125f, 0, 0, dtf, 0, nullB, nullptr);
    gemm_bt<128><<<dim3(8, 64, 2), 256, 0, stream>>>(
        Xb, WT, Buf, D, D, D, D, 0L, 0L, 0L, 0L, 0L, 0L,
        1.0f, 0, 0, dtf, 0, VwT, VbS);
    xpose_cast<<<dim3(16, 32, 4), 256, 0, stream>>>(
        VbS, VbT, nullptr, S, D, 0L, (long)S * D, (long)D * S, 0L, dtf, 0);

    for (int b0 = 0; b0 < B; b0 += ZB) {
        for (int q0 = 0; q0 < S; q0 += CH) {
            const int base = q0 / 128, R = CH / 128;
            const int ntiles = R * (base + 1) + R * (R - 1) / 2;

            gemm_bt<128><<<dim3(ntiles, 1, ZB), 256, 0, stream>>>(
                Buf, Xb, (void*)Sc, D, D, D, S,
                (long)b0 * S * D + (long)q0 * D, (long)b0 * S * D, 0L,
                (long)S * D, (long)S * D, (long)CH * S,
                1.0f, 1, q0, dtf, 1, nullB, nullptr);

            softmax_causal<<<dim3(CH, ZB), 256, 0, stream>>>(Sc, S, CH, q0);

            gemm_bt<128><<<dim3(8, CH / 128, ZB), 256, 0, stream>>>(
                (const unsigned short*)Sc, VbT, d_out, S, 2 * S, S, D,
                0L, (long)b0 * D * S, (long)b0 * S * D + (long)q0 * D,
                (long)CH * 2 * S, (long)D * S, (long)S * D,
                1.0f, 2, q0, dtf, 2, nullB, nullptr);
        }
    }
}

// Round 12
// 252.649 us; speedup vs baseline: 1.0233x; 1.0233x over previous
//
// Self-attention (B=4,S=2048,D=1024) via W-fused GEMM pipeline.
#include <hip/hip_runtime.h>
#include <hip/hip_bf16.h>

typedef __attribute__((ext_vector_type(8))) __bf16 bf16x8;
typedef __attribute__((ext_vector_type(8))) short short8;
typedef __attribute__((ext_vector_type(4))) float f32x4;

#define BK 64
// Square TM x TM tiles (TM = 128 main, 64 for the tiny WT GEMM), BK=64,
// double-buffered 2-phase — the proven round-2/5/9 schedule. Round 6 measured
// BK=32 as a regression. LDS at TM=128: 64KB -> 2 blocks/CU.
//
// Bank swizzle (both-sides, rule #21/m173), BK=64 -> 8 16B slots/row:
// logical col16 c of row r stored at phys slot c ^ (r&7). Staging lane l
// (chunk row l>>3, slot l&7) fetches global col16 (l&7)^(l>>3); ds_read of
// logical slot q at row 16*i+lrow uses slot q^(lrow&7). Measured
// SQ_LDS_BANK_CONFLICT = 0 (rounds 2/5/9/10/11).
//
// r10: paired dual-B raised FETCH (L2 thrash) -> z-form dual (Config A only).
// r11: mode-3 distance-256 causal balance: small win, kept.
// r12: VbT computed DIRECTLY as a GEMM (A=VwT, Bt=Xb, ldc=S) when workspace
// allows a dedicated 16MB VbT region -> deletes the xpose round-trip (48MB
// traffic) and the d_out scratch. detect folded into prep (-1 launch).

__device__ inline unsigned short f2bf(float f) {  // RNE fp32->bf16
    union { float f; unsigned u; } v; v.f = f;
    unsigned r = (v.u + 0x7FFFu + ((v.u >> 16) & 1u)) >> 16;
    return (unsigned short)r;
}

// async global->LDS, 16B per lane. g: per-lane global addr; l: wave-uniform LDS base.
__device__ __forceinline__ void gld16(const void* g, void* l) {
    __builtin_amdgcn_global_load_lds(
        (const __attribute__((address_space(1))) unsigned int*)g,
        (__attribute__((address_space(3))) unsigned int*)l, 16, 0, 0);
}

// dtype probe core: even ushorts of bf16 N(0,1) data have sane exponents
// (~100% in [0x60,0x88]); of fp32 data they are uniform mantissa bits (~16%).
// Returns block-uniform dt (0 = bf16 world, 1 = fp32 world).
__device__ inline int detect_dt(const unsigned short* x, int tid, int* red)
{
    int cnt = 0;
    for (int i = tid; i < 1024; i += 256) {
        unsigned e = (x[2 * i] >> 7) & 0xFFu;
        cnt += (e >= 0x60u && e <= 0x88u) ? 1 : 0;
    }
    #pragma unroll
    for (int o = 32; o >= 1; o >>= 1) cnt += __shfl_xor(cnt, o, 64);
    if ((tid & 63) == 0) red[tid >> 6] = cnt;
    __syncthreads();
    return (red[0] + red[1] + red[2] + red[3] >= 512) ? 0 : 1;
}

__global__ void detect_dtype(const unsigned short* __restrict__ x, int* __restrict__ flag)
{
    __shared__ int red[4];
    const int dt = detect_dt(x, threadIdx.x, red);
    if (threadIdx.x == 0) *flag = dt;
}

// All input prep in ONE launch (flat grid, range-dispatched). Each block
// self-detects dtype (deterministic -> uniform); block 0 publishes dtf for
// the downstream GEMMs (stream order guarantees visibility).
//   [0, nbX)            : Xb  = bf16(x)        straight copy, 8 elems/thread
//   [nbX, nbX+nbW)      : QwB = bf16(Qw)       straight copy
//   [nbX+nbW, nbX+2nbW) : KwB = bf16(Kw)       straight copy
//   [nbX+2nbW, +256)    : VwT = bf16(Vw)^T     64x64 LDS-tile transpose
__global__ __launch_bounds__(256)
void prep(const void* __restrict__ x, const void* __restrict__ Qw,
          const void* __restrict__ Kw, const void* __restrict__ Vw,
          unsigned short* __restrict__ Xb, unsigned short* __restrict__ QwB,
          unsigned short* __restrict__ KwB, unsigned short* __restrict__ VwT,
          long nX, long nW, int Dd, int* __restrict__ dtf)
{
    const int bid = blockIdx.x;
    const int tid = threadIdx.x;
    __shared__ int red[4];
    const int dt = detect_dt((const unsigned short*)x, tid, red);
    if (bid == 0 && tid == 0) *dtf = dt;

    const int nbX = (int)(nX >> 11);   // 2048 elems per copy block
    const int nbW = (int)(nW >> 11);
    __shared__ unsigned short tbuf[64][65];

    if (bid < nbX + 2 * nbW) {
        const void* s; unsigned short* d; long i;
        if (bid < nbX)            { s = x;  d = Xb;  i = ((long)bid << 11) + tid * 8; }
        else if (bid < nbX + nbW) { s = Qw; d = QwB; i = ((long)(bid - nbX) << 11) + tid * 8; }
        else                      { s = Kw; d = KwB; i = ((long)(bid - nbX - nbW) << 11) + tid * 8; }
        union { short8 v; unsigned short u[8]; } o;
        if (dt) {
            f32x4 a = *(const f32x4*)((const float*)s + i);
            f32x4 b = *(const f32x4*)((const float*)s + i + 4);
            #pragma unroll
            for (int j = 0; j < 4; j++) { o.u[j] = f2bf(a[j]); o.u[4 + j] = f2bf(b[j]); }
        } else {
            o.v = *(const short8*)((const short*)s + i);
        }
        *(short8*)(d + i) = o.v;
        return;
    }
    const int t64 = bid - (nbX + 2 * nbW);          // 0..(Dd/64)^2-1
    const int c0 = (t64 & 15) * 64, r0 = (t64 >> 4) * 64;
    #pragma unroll
    for (int it = 0; it < 16; it++) {
        int idx = it * 256 + tid;
        int r = idx >> 6, c = idx & 63;
        long e = (long)(r0 + r) * Dd + (c0 + c);
        tbuf[r][c] = dt ? f2bf(((const float*)Vw)[e]) : ((const unsigned short*)Vw)[e];
    }
    __syncthreads();
    #pragma unroll
    for (int it = 0; it < 16; it++) {
        int idx = it * 256 + tid;
        int r = idx >> 6, c = idx & 63;
        VwT[(long)(c0 + r) * Dd + (r0 + c)] = tbuf[c][r];
    }
}

// C = A @ Bt^T, all operands bf16. A [M][K] (lda), Bt [N][K] (ldb);
// offsets/strides in ELEMENTS. outKind: 0 bf16, 1 fp32, 2 external-dtype.
// mode 0: plain (XCD remap); z-form dual-B if Bt2 != null (blockIdx.z==1
//   switches to Bt2/C2 — Config A only).
// mode 1: enumerated causal tiles (triangle decode of blockIdx.x).
// mode 2: causal k-limit, adjacent-id heavy/light pairing (fallback path).
// mode 3: causal k-limit, distance-256 complementary pairing over a flat
//   512-block grid (Config A/A+ out-GEMM; assumes 16mt x 8nt x 4z, q0=0).
//   j = lin<256 ? lin : 767-lin; blocks lin and lin+256 get jobs j and 511-j
//   -> kmax sum = 128*17 = const under breadth-first CU filling.
template <int TM>
__global__ __launch_bounds__(256, 2)
void gemm_bt(const unsigned short* __restrict__ A, const unsigned short* __restrict__ Bt,
             void* __restrict__ Call, int K, int lda, int ldb, int ldc,
             long oA, long oB, long oC, long sA, long sB, long sC,
             float scale, int mode, int q0,
             const int* __restrict__ dtf, int outKind,
             const unsigned short* __restrict__ Bt2, void* __restrict__ C2)
{
    constexpr int NI = TM / 32;           // 16x16 frags per wave dim
    const int dt = *dtf;
    int zSel = blockIdx.z;
    if (mode != 3 && Bt2 && zSel) { Bt = Bt2; Call = C2; }   // z-form dual

    int mt, nt;
    if (mode == 3) {
        const int lin = blockIdx.x;                  // 512 blocks
        const int j = (lin < 256) ? lin : 767 - lin; // kmax-desc job index
        mt = 15 - (j >> 5);                          // j=0 -> heaviest (mt=15)
        zSel = (j >> 3) & 3;
        nt = j & 7;
    } else if (mode == 2) {
        const int nwg2 = gridDim.x * gridDim.y;
        const int h = blockIdx.y * gridDim.x + blockIdx.x;
        const int u = h >> 1;
        const int rank = (h & 1) ? (nwg2 - 1 - u) : u;   // 0 = heaviest
        mt = (gridDim.y - 1) - (rank / (int)gridDim.x);
        nt = rank % (int)gridDim.x;
    } else {
        // XCD-aware bijective remap (T1, m204 formula).
        const int nwg = gridDim.x * gridDim.y;
        int lin = blockIdx.y * gridDim.x + blockIdx.x;
        const int q = nwg >> 3, r = nwg & 7;
        const int xcd = lin & 7, idx = lin >> 3;
        lin = (xcd < r ? xcd * (q + 1) : r * (q + 1) + (xcd - r) * q) + idx;
        if (mode == 1) {  // decode linear id over the causal tile triangle
            int rem = lin, rr = 0, w = q0 / TM + 1;
            while (rem >= w) { rem -= w; rr++; w++; }
            mt = rr; nt = rem;
        } else { mt = lin / gridDim.x; nt = lin % gridDim.x; }
    }
    const long aBase = oA + (long)zSel * sA;
    const long bBase = oB + (long)zSel * sB;
    const long cBase = oC + (long)zSel * sC;
    const int m0 = mt * TM;
    const int n0 = nt * TM;
    int kmax = K;
    if (mode >= 2) kmax = min(K, q0 + m0 + TM);

    __shared__ __align__(16) short As[2][TM * BK];
    __shared__ __align__(16) short Bs[2][TM * BK];

    const int tid  = threadIdx.x;
    const int wave = tid >> 6;
    const int lane = tid & 63;
    const int wm = (wave >> 1) * (TM / 2);
    const int wn = (wave & 1) * (TM / 2);
    const int lrow = lane & 15;
    const int quad = lane >> 4;

    // Staging: per wave TM/4 rows of A and of B per K-step, in 8-row/1KB gld16
    // chunks. lane l -> chunk row l>>3, pre-swizzled global col16 (l&7)^(l>>3).
    const int sRow = lane >> 3;
    const int sCol = ((lane & 7) ^ sRow) * 8;  // elements
    const long gA = aBase + (long)(m0 + wave * (TM / 4) + sRow) * lda + sCol;
    const long gB = bBase + (long)(n0 + wave * (TM / 4) + sRow) * ldb + sCol;

    auto stage = [&](int buf, int k0) {
        short* dA = &As[buf][wave * (TM / 4) * BK];
        short* dB = &Bs[buf][wave * (TM / 4) * BK];
        const unsigned short* pA = A + gA + k0;
        const unsigned short* pB = Bt + gB + k0;
        #pragma unroll
        for (int c = 0; c < TM / 32; c++) {
            gld16(pA + (long)(c * 8) * lda, dA + c * 8 * BK);
            gld16(pB + (long)(c * 8) * ldb, dB + c * 8 * BK);
        }
    };

    f32x4 acc[NI][NI];
    #pragma unroll
    for (int i = 0; i < NI; i++)
        #pragma unroll
        for (int j = 0; j < NI; j++) {
            f32x4 zero = {0.f, 0.f, 0.f, 0.f};
            acc[i][j] = zero;
        }

    // ds_read physical col16 slots for the two K-halves (lane-constant:
    // row = wm + i*16 + lrow, and wm/i*16 are multiples of 8 -> row&7 == lrow&7).
    const int rq  = lrow & 7;
    const int pc0 = (quad ^ rq) * 8;
    const int pc1 = ((quad + 4) ^ rq) * 8;

    stage(0, 0);
    __syncthreads();    // vmcnt(0) drained before barrier -> tile 0 ready
    int cur = 0;

    for (int k0 = 0; k0 < kmax; k0 += BK) {
        const int kn = k0 + BK;
        if (kn < kmax) stage(cur ^ 1, kn);   // prefetch in flight during compute

        const short* rA = &As[cur][0];
        const short* rB = &Bs[cur][0];
        bf16x8 af[NI], bfr[NI];
        #pragma unroll
        for (int i = 0; i < NI; i++) {
            af[i]  = *(const bf16x8*)&rA[(wm + i * 16 + lrow) * BK + pc0];
            bfr[i] = *(const bf16x8*)&rB[(wn + i * 16 + lrow) * BK + pc0];
        }
        #pragma unroll
        for (int i = 0; i < NI; i++)
            #pragma unroll
            for (int j = 0; j < NI; j++)
                acc[i][j] = __builtin_amdgcn_mfma_f32_16x16x32_bf16(af[i], bfr[j], acc[i][j], 0, 0, 0);
        #pragma unroll
        for (int i = 0; i < NI; i++) {
            af[i]  = *(const bf16x8*)&rA[(wm + i * 16 + lrow) * BK + pc1];
            bfr[i] = *(const bf16x8*)&rB[(wn + i * 16 + lrow) * BK + pc1];
        }
        #pragma unroll
        for (int i = 0; i < NI; i++)
            #pragma unroll
            for (int j = 0; j < NI; j++)
                acc[i][j] = __builtin_amdgcn_mfma_f32_16x16x32_bf16(af[i], bfr[j], acc[i][j], 0, 0, 0);

        __syncthreads();   // drains prefetch (vmcnt) + readers (lgkm); swap
        cur ^= 1;
    }

    const int oF32 = (outKind == 1) | ((outKind == 2) & dt);
    // C/D layout (m89-verified): col = lane&15, row = quad*4 + reg
    #pragma unroll
    for (int i = 0; i < NI; i++) {
        const int mr = m0 + wm + i * 16 + quad * 4;
        #pragma unroll
        for (int j = 0; j < NI; j++) {
            const int nc = n0 + wn + j * 16 + lrow;
            #pragma unroll
            for (int r = 0; r < 4; r++) {
                const long ofs = cBase + (long)(mr + r) * ldc + nc;
                const float v = acc[i][j][r] * scale;
                if (oF32) ((float*)Call)[ofs] = v;
                else      ((unsigned short*)Call)[ofs] = f2bf(v);
            }
        }
    }
}

// One-pass cast/transpose: src [R][C] (dtype per flag if srcExt).
// dT (optional): bf16 [C][R] transposed. dC (optional): bf16 [R][C] straight copy.
__global__ __launch_bounds__(256)
void xpose_cast(const void* __restrict__ src, unsigned short* __restrict__ dT,
                unsigned short* __restrict__ dC, int R, int C,
                long oS, long sS, long sDT, long sDC,
                const int* __restrict__ dtf, int srcExt)
{
    const int dt = srcExt ? *dtf : 0;
    const int b = blockIdx.z;
    const long sb = oS + (long)b * sS;
    __shared__ unsigned short t[64][65];
    const int c0 = blockIdx.x * 64, r0 = blockIdx.y * 64;
    const int tid = threadIdx.x;
    #pragma unroll
    for (int it = 0; it < 16; it++) {
        int idx = it * 256 + tid;
        int r = idx >> 6, c = idx & 63;
        long e = sb + (long)(r0 + r) * C + (c0 + c);
        unsigned short v = dt ? f2bf(((const float*)src)[e]) : ((const unsigned short*)src)[e];
        t[r][c] = v;
        if (dC) dC[(long)b * sDC + (long)(r0 + r) * C + (c0 + c)] = v;
    }
    if (!dT) return;
    __syncthreads();
    #pragma unroll
    for (int it = 0; it < 16; it++) {
        int idx = it * 256 + tid;
        int r = idx >> 6, c = idx & 63;
        dT[(long)b * sDT + (long)(c0 + r) * R + (r0 + c)] = t[c][r];
    }
}

// Sc chunk fp32 [ZB][CH][S]; row (global q0+r) softmaxed, written back IN PLACE
// as bf16 P in the first half of its own fp32 row (P lda = 2S). Vectorized
// (G13): 8 contiguous elems/thread, f32x4 x2 loads + short8 store. Store guard
// is uniform over the 8-group (limit % 128 == 0, j0 % 8 == 0). Elements >=
// limit are never read by the out-GEMM; [n, limit) masked to 0 before pack.
// Beyond-n loads may hit stale ws bytes (finite or NaN) — masked to -1e30
// before any arithmetic, so NaN never propagates.
__global__ __launch_bounds__(256)
void softmax_causal(float* __restrict__ Sc, int S, int CH, int q0)
{
    const int r = blockIdx.x, z = blockIdx.y;
    float* srow = Sc + ((long)z * CH + r) * S;
    unsigned short* prow = (unsigned short*)srow;
    const int n = q0 + r + 1;
    const int limit = q0 + (r & ~127) + 128;   // tile-aligned causal bound
    const int tid = threadIdx.x;
    const int lane = tid & 63, wave = tid >> 6;
    const int j0 = tid * 8;
    __shared__ float red[4];

    float v[8];
    {
        f32x4 a = *(const f32x4*)(srow + j0);
        f32x4 b = *(const f32x4*)(srow + j0 + 4);
        #pragma unroll
        for (int c = 0; c < 4; c++) { v[c] = a[c]; v[4 + c] = b[c]; }
    }
    float lm = -1e30f;
    #pragma unroll
    for (int c = 0; c < 8; c++) {
        v[c] = (j0 + c < n) ? v[c] : -1e30f;
        lm = fmaxf(lm, v[c]);
    }
    #pragma unroll
    for (int o = 32; o >= 1; o >>= 1) lm = fmaxf(lm, __shfl_xor(lm, o, 64));
    if (lane == 0) red[wave] = lm;
    __syncthreads();
    const float m = fmaxf(fmaxf(red[0], red[1]), fmaxf(red[2], red[3]));
    __syncthreads();

    float ev[8];
    float ls = 0.f;
    #pragma unroll
    for (int c = 0; c < 8; c++) {
        float e = (j0 + c < n) ? __expf(v[c] - m) : 0.f;
        ev[c] = e;
        ls += e;
    }
    #pragma unroll
    for (int o = 32; o >= 1; o >>= 1) ls += __shfl_xor(ls, o, 64);
    if (lane == 0) red[wave] = ls;
    __syncthreads();   // all fp32 reads done before aliasing bf16 writes
    const float inv = 1.0f / (red[0] + red[1] + red[2] + red[3]);

    if (j0 < limit) {
        union { short8 s; unsigned short u[8]; } o;
        #pragma unroll
        for (int c = 0; c < 8; c++) o.u[c] = f2bf(ev[c] * inv);
        *(short8*)(prow + j0) = o.s;
    }
}

__global__ __launch_bounds__(256)
void fill_zero(void* o, long n, const int* dtf)
{
    long i = (long)blockIdx.x * 256 + threadIdx.x;
    if (i < n) {
        if (*dtf) ((float*)o)[i] = 0.f;
        else ((unsigned short*)o)[i] = 0;
    }
}

extern "C" void kernel_launch(void* const* d_in, const int* in_sizes, int n_in,
                              void* d_out, int out_size, void* d_ws, size_t ws_size,
                              hipStream_t stream)
{
    const int B = 4, S = 2048, D = 1024;
    const void* x  = d_in[0];
    const void* Qw = d_in[1];
    const void* Kw = d_in[2];
    const void* Vw = d_in[3];
    (void)in_sizes; (void)n_in; (void)out_size;

    // Algebra: scores = X (Qw Kw^T) X^T / 32 ; out = P (X Vw).
    //   prep: Xb/QwB/KwB/VwT + dtype detect, one launch
    //   WT  = Kw @ Qw^T / 32          (256 blocks)
    //   VbT = VwT @ Xb^T (ldc=S)      (A+ only: direct, no transpose pass)
    //   G   = Xb @ WT^T -> Buf
    //   Sc  = G @ Xb^T (causal) -> softmax in place -> P
    //   out = P @ VbT^T (causal mode 3) -> d_out
    int* dtf = (int*)d_ws;
    char* p = (char*)d_ws + 4096;
    const size_t MB = (size_t)1 << 20;
    const unsigned short* nullB = nullptr;

    const long nOut = (long)B * S * D;
    const long nX = (long)B * S * D;
    const long nW = (long)D * D;
    const int prepBlocks = (int)(nX >> 11) + 2 * (int)(nW >> 11) + (D / 64) * (D / 64);

    // ---- Config A+: dedicated VbT region (116MB+4KB).
    // ws: dtf | QwB 2MB | KwB 2MB | Xb 16MB | Buf 16MB (G) | VbT 16MB |
    //     Sc fp32 64MB (WT bf16 in first 2MB, VwT in next 2MB — both consumed
    //     before the Sc GEMM overwrites them).
    const size_t needAp = 4096 + 52 * MB + (size_t)B * S * S * 4;
    if (ws_size >= needAp) {
        unsigned short* QwB = (unsigned short*)p;
        unsigned short* KwB = (unsigned short*)(p + 2 * MB);
        unsigned short* Xb  = (unsigned short*)(p + 4 * MB);
        unsigned short* Buf = (unsigned short*)(p + 20 * MB);
        unsigned short* VbT = (unsigned short*)(p + 36 * MB);
        float* Sc = (float*)(p + 52 * MB);
        unsigned short* WT  = (unsigned short*)Sc;            // Sc head
        unsigned short* VwT = (unsigned short*)((char*)Sc + 2 * MB);

        prep<<<dim3(prepBlocks), 256, 0, stream>>>(
            x, Qw, Kw, Vw, Xb, QwB, KwB, VwT, nX, nW, D, dtf);
        // WT = Kw @ Qw^T / 32   [256 blocks]
        gemm_bt<64><<<dim3(16, 16, 1), 256, 0, stream>>>(
            KwB, QwB, WT, D, D, D, D, 0L, 0L, 0L, 0L, 0L, 0L,
            0.03125f, 0, 0, dtf, 0, nullB, nullptr);
        // VbT[b][d][s] = sum_k VwT[d][k] * Xb[b][s][k]   [512 blocks, direct]
        gemm_bt<128><<<dim3(16, 8, 4), 256, 0, stream>>>(
            VwT, Xb, VbT, D, D, D, S,
            0L, 0L, 0L, 0L, (long)S * D, (long)D * S,
            1.0f, 0, 0, dtf, 0, nullB, nullptr);
        // G = Xb @ WT^T -> Buf   [512 blocks]
        gemm_bt<128><<<dim3(8, 64, 1), 256, 0, stream>>>(
            Xb, WT, Buf, D, D, D, D, 0L, 0L, 0L, 0L, 0L, 0L,
            1.0f, 0, 0, dtf, 0, nullB, nullptr);
        // Sc = G @ Xb^T  (enumerated causal tiles)   [544 blocks]
        gemm_bt<128><<<dim3(136, 1, 4), 256, 0, stream>>>(
            Buf, Xb, (void*)Sc, D, D, D, S,
            0L, 0L, 0L, (long)S * D, (long)S * D, (long)S * S,
            1.0f, 1, 0, dtf, 1, nullB, nullptr);
        softmax_causal<<<dim3(S, 4), 256, 0, stream>>>(Sc, S, S, 0);
        // out = P @ VbT^T (mode 3: flat 512 grid, distance-256 balance)
        gemm_bt<128><<<dim3(512, 1, 1), 256, 0, stream>>>(
            (const unsigned short*)Sc, VbT, d_out, S, 2 * S, S, D,
            0L, 0L, 0L, (long)2 * S * S, (long)D * S, (long)S * D,
            1.0f, 3, 0, dtf, 2, nullB, nullptr);
        return;
    }

    // ---- Config A: r11 structure (100MB+4KB) — z-form dual + xpose.
    const size_t needA = 4096 + 36 * MB + (size_t)B * S * S * 4;
    if (ws_size >= needA) {
        unsigned short* QwB = (unsigned short*)p;
        unsigned short* KwB = (unsigned short*)(p + 2 * MB);
        unsigned short* Xb  = (unsigned short*)(p + 4 * MB);
        unsigned short* Buf = (unsigned short*)(p + 20 * MB);
        float* Sc = (float*)(p + 36 * MB);
        unsigned short* WT  = (unsigned short*)Sc;            // Sc head
        unsigned short* VwT = (unsigned short*)((char*)Sc + 2 * MB);
        unsigned short* VbT = Xb;                             // Xb dead after Sc
        unsigned short* VbS = (unsigned short*)d_out;         // Vb scratch

        prep<<<dim3(prepBlocks), 256, 0, stream>>>(
            x, Qw, Kw, Vw, Xb, QwB, KwB, VwT, nX, nW, D, dtf);
        gemm_bt<64><<<dim3(16, 16, 1), 256, 0, stream>>>(
            KwB, QwB, WT, D, D, D, D, 0L, 0L, 0L, 0L, 0L, 0L,
            0.03125f, 0, 0, dtf, 0, nullB, nullptr);
        // G = Xb @ WT^T -> Buf || Vb = Xb @ VwT^T -> VbS  [z-form, 1024 blocks]
        gemm_bt<128><<<dim3(8, 64, 2), 256, 0, stream>>>(
            Xb, WT, Buf, D, D, D, D, 0L, 0L, 0L, 0L, 0L, 0L,
            1.0f, 0, 0, dtf, 0, VwT, VbS);
        gemm_bt<128><<<dim3(136, 1, 4), 256, 0, stream>>>(
            Buf, Xb, (void*)Sc, D, D, D, S,
            0L, 0L, 0L, (long)S * D, (long)S * D, (long)S * S,
            1.0f, 1, 0, dtf, 1, nullB, nullptr);
        softmax_causal<<<dim3(S, 4), 256, 0, stream>>>(Sc, S, S, 0);
        xpose_cast<<<dim3(16, 32, 4), 256, 0, stream>>>(
            VbS, VbT, nullptr, S, D, 0L, (long)S * D, (long)D * S, 0L, dtf, 0);
        gemm_bt<128><<<dim3(512, 1, 1), 256, 0, stream>>>(
            (const unsigned short*)Sc, VbT, d_out, S, 2 * S, S, D,
            0L, 0L, 0L, (long)2 * S * S, (long)D * S, (long)S * D,
            1.0f, 3, 0, dtf, 2, nullB, nullptr);
        return;
    }

    // ---- Generic chunked fallback: fixed = 56MB + Sc chunk. Vb staged
    // through d_out (fully consumed into VbT before the loop writes d_out).
    const int cfgs[6][2] = {{4,1024},{2,1024},{1,1024},{1,512},{1,256},{1,128}};
    int ZB = 0, CH = 0;
    for (int i = 0; i < 6; i++) {
        size_t need = 4096 + 56 * MB + (size_t)cfgs[i][0] * cfgs[i][1] * S * 4;
        if (need <= ws_size) { ZB = cfgs[i][0]; CH = cfgs[i][1]; break; }
    }
    if (ZB == 0) {  // diagnostic zeros
        detect_dtype<<<1, 256, 0, stream>>>((const unsigned short*)x, dtf);
        fill_zero<<<dim3((unsigned)((nOut + 255) / 256)), 256, 0, stream>>>(d_out, nOut, dtf);
        return;
    }

    unsigned short* QwB = (unsigned short*)p;
    unsigned short* KwB = (unsigned short*)(p + 2 * MB);
    unsigned short* WT  = (unsigned short*)(p + 4 * MB);
    unsigned short* VwT = (unsigned short*)(p + 6 * MB);
    unsigned short* Xb  = (unsigned short*)(p + 8 * MB);
    unsigned short* VbT = (unsigned short*)(p + 24 * MB);
    unsigned short* Buf = (unsigned short*)(p + 40 * MB);
    float* Sc = (float*)(p + 56 * MB);
    unsigned short* VbS = (unsigned short*)d_out;   // Vb scratch (dead pre-out)

    prep<<<dim3(prepBlocks), 256, 0, stream>>>(
        x, Qw, Kw, Vw, Xb, QwB, KwB, VwT, nX, nW, D, dtf);
    gemm_bt<64><<<dim3(16, 16, 1), 256, 0, stream>>>(
        KwB, QwB, WT, D, D, D, D, 0L, 0L, 0L, 0L, 0L, 0L,
        0.03125f, 0, 0, dtf, 0, nullB, nullptr);
    gemm_bt<128><<<dim3(8, 64, 2), 256, 0, stream>>>(
        Xb, WT, Buf, D, D, D, D, 0L, 0L, 0L, 0L, 0L, 0L,
        1.0f, 0, 0, dtf, 0, VwT, VbS);
    xpose_cast<<<dim3(16, 32, 4), 256, 0, stream>>>(
        VbS, VbT, nullptr, S, D, 0L, (long)S * D, (long)D * S, 0L, dtf, 0);

    for (int b0 = 0; b0 < B; b0 += ZB) {
        for (int q0 = 0; q0 < S; q0 += CH) {
            const int base = q0 / 128, R = CH / 128;
            const int ntiles = R * (base + 1) + R * (R - 1) / 2;

            gemm_bt<128><<<dim3(ntiles, 1, ZB), 256, 0, stream>>>(
                Buf, Xb, (void*)Sc, D, D, D, S,
                (long)b0 * S * D + (long)q0 * D, (long)b0 * S * D, 0L,
                (long)S * D, (long)S * D, (long)CH * S,
                1.0f, 1, q0, dtf, 1, nullB, nullptr);

            softmax_causal<<<dim3(CH, ZB), 256, 0, stream>>>(Sc, S, CH, q0);

            gemm_bt<128><<<dim3(8, CH / 128, ZB), 256, 0, stream>>>(
                (const unsigned short*)Sc, VbT, d_out, S, 2 * S, S, D,
                0L, (long)b0 * D * S, (long)b0 * S * D + (long)q0 * D,
                (long)CH * 2 * S, (long)D * S, (long)S * D,
                1.0f, 2, q0, dtf, 2, nullB, nullptr);
        }
    }
}

// Round 13
// 248.071 us; speedup vs baseline: 1.0421x; 1.0185x over previous
//
// Self-attention (B=4,S=2048,D=1024) via W-fused GEMM pipeline.
#include <hip/hip_runtime.h>
#include <hip/hip_bf16.h>

typedef __attribute__((ext_vector_type(8))) __bf16 bf16x8;
typedef __attribute__((ext_vector_type(8))) short short8;
typedef __attribute__((ext_vector_type(4))) float f32x4;

#define BK 64
// TM x TM tiles (128 main, 64 WT), BK=64, dbuf 2-phase (proven r2/5/9).
// r6: BK=32 regression. LDS 64KB -> 2 blocks/CU.
// Bank swizzle (rule #21/m173): col16 c of row r at phys slot c^(r&7);
// staging lane l fetches global col16 (l&7)^(l>>3); ds_read uses q^(lrow&7).
// SQ_LDS_BANK_CONFLICT = 0 measured (r2/5/9/10/11/12).
// r10: paired dual thrashed L2 -> z-form. r11: mode-3 distance-256 balance.
// r12: VbT direct GEMM. r13: bf16 Sc (halves score-side traffic), softmax
// causal read-guard, G+VbT fused into one 1024-block mode-4 launch (no tail).

__device__ inline unsigned short f2bf(float f) {  // RNE fp32->bf16
    union { float f; unsigned u; } v; v.f = f;
    unsigned r = (v.u + 0x7FFFu + ((v.u >> 16) & 1u)) >> 16;
    return (unsigned short)r;
}

// async global->LDS, 16B per lane. g: per-lane global addr; l: wave-uniform LDS base.
__device__ __forceinline__ void gld16(const void* g, void* l) {
    __builtin_amdgcn_global_load_lds(
        (const __attribute__((address_space(1))) unsigned int*)g,
        (__attribute__((address_space(3))) unsigned int*)l, 16, 0, 0);
}

// dtype probe core: even ushorts of bf16 N(0,1) data have sane exponents
// (~100% in [0x60,0x88]); of fp32 data they are uniform mantissa bits (~16%).
__device__ inline int detect_dt(const unsigned short* x, int tid, int* red)
{
    int cnt = 0;
    for (int i = tid; i < 1024; i += 256) {
        unsigned e = (x[2 * i] >> 7) & 0xFFu;
        cnt += (e >= 0x60u && e <= 0x88u) ? 1 : 0;
    }
    #pragma unroll
    for (int o = 32; o >= 1; o >>= 1) cnt += __shfl_xor(cnt, o, 64);
    if ((tid & 63) == 0) red[tid >> 6] = cnt;
    __syncthreads();
    return (red[0] + red[1] + red[2] + red[3] >= 512) ? 0 : 1;
}

__global__ void detect_dtype(const unsigned short* __restrict__ x, int* __restrict__ flag)
{
    __shared__ int red[4];
    const int dt = detect_dt(x, threadIdx.x, red);
    if (threadIdx.x == 0) *flag = dt;
}

// All input prep in ONE launch (flat grid, range-dispatched). Each block
// self-detects dtype (deterministic -> uniform); block 0 publishes dtf.
//   [0, nbX)            : Xb  = bf16(x)
//   [nbX, nbX+nbW)      : QwB = bf16(Qw)
//   [nbX+nbW, nbX+2nbW) : KwB = bf16(Kw)
//   [nbX+2nbW, +256)    : VwT = bf16(Vw)^T  64x64 LDS-tile transpose
__global__ __launch_bounds__(256)
void prep(const void* __restrict__ x, const void* __restrict__ Qw,
          const void* __restrict__ Kw, const void* __restrict__ Vw,
          unsigned short* __restrict__ Xb, unsigned short* __restrict__ QwB,
          unsigned short* __restrict__ KwB, unsigned short* __restrict__ VwT,
          long nX, long nW, int Dd, int* __restrict__ dtf)
{
    const int bid = blockIdx.x;
    const int tid = threadIdx.x;
    __shared__ int red[4];
    const int dt = detect_dt((const unsigned short*)x, tid, red);
    if (bid == 0 && tid == 0) *dtf = dt;

    const int nbX = (int)(nX >> 11);   // 2048 elems per copy block
    const int nbW = (int)(nW >> 11);
    __shared__ unsigned short tbuf[64][65];

    if (bid < nbX + 2 * nbW) {
        const void* s; unsigned short* d; long i;
        if (bid < nbX)            { s = x;  d = Xb;  i = ((long)bid << 11) + tid * 8; }
        else if (bid < nbX + nbW) { s = Qw; d = QwB; i = ((long)(bid - nbX) << 11) + tid * 8; }
        else                      { s = Kw; d = KwB; i = ((long)(bid - nbX - nbW) << 11) + tid * 8; }
        union { short8 v; unsigned short u[8]; } o;
        if (dt) {
            f32x4 a = *(const f32x4*)((const float*)s + i);
            f32x4 b = *(const f32x4*)((const float*)s + i + 4);
            #pragma unroll
            for (int j = 0; j < 4; j++) { o.u[j] = f2bf(a[j]); o.u[4 + j] = f2bf(b[j]); }
        } else {
            o.v = *(const short8*)((const short*)s + i);
        }
        *(short8*)(d + i) = o.v;
        return;
    }
    const int t64 = bid - (nbX + 2 * nbW);          // 0..(Dd/64)^2-1
    const int c0 = (t64 & 15) * 64, r0 = (t64 >> 4) * 64;
    #pragma unroll
    for (int it = 0; it < 16; it++) {
        int idx = it * 256 + tid;
        int r = idx >> 6, c = idx & 63;
        long e = (long)(r0 + r) * Dd + (c0 + c);
        tbuf[r][c] = dt ? f2bf(((const float*)Vw)[e]) : ((const unsigned short*)Vw)[e];
    }
    __syncthreads();
    #pragma unroll
    for (int it = 0; it < 16; it++) {
        int idx = it * 256 + tid;
        int r = idx >> 6, c = idx & 63;
        VwT[(long)(c0 + r) * Dd + (r0 + c)] = tbuf[c][r];
    }
}

// C = A @ Bt^T, all operands bf16. A [M][K] (lda), Bt [N][K] (ldb);
// offsets/strides in ELEMENTS. outKind: 0 bf16, 1 fp32, 2 external-dtype.
// mode 0: plain (XCD remap); z-form dual-B if Bt2 != null.
// mode 1: enumerated causal tiles (triangle decode).
// mode 2: causal k-limit, adjacent-id pairing (fallback path).
// mode 3: causal k-limit, distance-256 complementary pairing, flat 512 grid
//   (assumes 16mt x 8nt x 4z, q0=0).
// mode 4: FUSED uniform pair over flat 1024 grid (zero scheduling tail):
//   remapped lin < 512 -> G (A,Bt,Call; 64mt x 8nt, z=0, bases 0);
//   lin >= 512 -> VbT (A2,Bt2,C2,ldc2; j2=lin-512: z=j2>>7, mt=(j2&127)>>4,
//   nt=j2&15; bBase=z*sB, cBase=z*sC). Both full-K.
template <int TM>
__global__ __launch_bounds__(256, 2)
void gemm_bt(const unsigned short* __restrict__ A, const unsigned short* __restrict__ Bt,
             void* __restrict__ Call, int K, int lda, int ldb, int ldc,
             long oA, long oB, long oC, long sA, long sB, long sC,
             float scale, int mode, int q0,
             const int* __restrict__ dtf, int outKind,
             const unsigned short* __restrict__ Bt2, void* __restrict__ C2,
             const unsigned short* __restrict__ A2, int ldc2)
{
    constexpr int NI = TM / 32;           // 16x16 frags per wave dim
    const int dt = *dtf;
    int zSel = blockIdx.z;
    if (mode == 0 && Bt2 && zSel) { Bt = Bt2; Call = C2; }   // z-form dual

    int mt, nt;
    if (mode == 4) {
        int lin = blockIdx.x;                        // 1024 blocks
        const int xcd = lin & 7, idx = lin >> 3;
        lin = xcd * 128 + idx;                       // bijective remap (nwg=1024)
        if (lin < 512) { mt = lin >> 3; nt = lin & 7; zSel = 0; }
        else {
            const int j2 = lin - 512;
            zSel = j2 >> 7;
            const int r2 = j2 & 127;
            mt = r2 >> 4; nt = r2 & 15;
            A = A2; Bt = Bt2; Call = C2; ldc = ldc2;
        }
    } else if (mode == 3) {
        const int lin = blockIdx.x;                  // 512 blocks
        const int j = (lin < 256) ? lin : 767 - lin; // kmax-desc job index
        mt = 15 - (j >> 5);                          // j=0 -> heaviest (mt=15)
        zSel = (j >> 3) & 3;
        nt = j & 7;
    } else if (mode == 2) {
        const int nwg2 = gridDim.x * gridDim.y;
        const int h = blockIdx.y * gridDim.x + blockIdx.x;
        const int u = h >> 1;
        const int rank = (h & 1) ? (nwg2 - 1 - u) : u;   // 0 = heaviest
        mt = (gridDim.y - 1) - (rank / (int)gridDim.x);
        nt = rank % (int)gridDim.x;
    } else {
        // XCD-aware bijective remap (T1, m204 formula).
        const int nwg = gridDim.x * gridDim.y;
        int lin = blockIdx.y * gridDim.x + blockIdx.x;
        const int q = nwg >> 3, r = nwg & 7;
        const int xcd = lin & 7, idx = lin >> 3;
        lin = (xcd < r ? xcd * (q + 1) : r * (q + 1) + (xcd - r) * q) + idx;
        if (mode == 1) {  // decode linear id over the causal tile triangle
            int rem = lin, rr = 0, w = q0 / TM + 1;
            while (rem >= w) { rem -= w; rr++; w++; }
            mt = rr; nt = rem;
        } else { mt = lin / gridDim.x; nt = lin % gridDim.x; }
    }
    const long aBase = oA + (long)zSel * sA;
    const long bBase = oB + (long)zSel * sB;
    const long cBase = oC + (long)zSel * sC;
    const int m0 = mt * TM;
    const int n0 = nt * TM;
    int kmax = K;
    if (mode == 2 || mode == 3) kmax = min(K, q0 + m0 + TM);

    __shared__ __align__(16) short As[2][TM * BK];
    __shared__ __align__(16) short Bs[2][TM * BK];

    const int tid  = threadIdx.x;
    const int wave = tid >> 6;
    const int lane = tid & 63;
    const int wm = (wave >> 1) * (TM / 2);
    const int wn = (wave & 1) * (TM / 2);
    const int lrow = lane & 15;
    const int quad = lane >> 4;

    // Staging: per wave TM/4 rows of A and of B per K-step, in 8-row/1KB gld16
    // chunks. lane l -> chunk row l>>3, pre-swizzled global col16 (l&7)^(l>>3).
    const int sRow = lane >> 3;
    const int sCol = ((lane & 7) ^ sRow) * 8;  // elements
    const long gA = aBase + (long)(m0 + wave * (TM / 4) + sRow) * lda + sCol;
    const long gB = bBase + (long)(n0 + wave * (TM / 4) + sRow) * ldb + sCol;

    auto stage = [&](int buf, int k0) {
        short* dA = &As[buf][wave * (TM / 4) * BK];
        short* dB = &Bs[buf][wave * (TM / 4) * BK];
        const unsigned short* pA = A + gA + k0;
        const unsigned short* pB = Bt + gB + k0;
        #pragma unroll
        for (int c = 0; c < TM / 32; c++) {
            gld16(pA + (long)(c * 8) * lda, dA + c * 8 * BK);
            gld16(pB + (long)(c * 8) * ldb, dB + c * 8 * BK);
        }
    };

    f32x4 acc[NI][NI];
    #pragma unroll
    for (int i = 0; i < NI; i++)
        #pragma unroll
        for (int j = 0; j < NI; j++) {
            f32x4 zero = {0.f, 0.f, 0.f, 0.f};
            acc[i][j] = zero;
        }

    // ds_read physical col16 slots for the two K-halves (lane-constant:
    // row = wm + i*16 + lrow, and wm/i*16 are multiples of 8 -> row&7 == lrow&7).
    const int rq  = lrow & 7;
    const int pc0 = (quad ^ rq) * 8;
    const int pc1 = ((quad + 4) ^ rq) * 8;

    stage(0, 0);
    __syncthreads();    // vmcnt(0) drained before barrier -> tile 0 ready
    int cur = 0;

    for (int k0 = 0; k0 < kmax; k0 += BK) {
        const int kn = k0 + BK;
        if (kn < kmax) stage(cur ^ 1, kn);   // prefetch in flight during compute

        const short* rA = &As[cur][0];
        const short* rB = &Bs[cur][0];
        bf16x8 af[NI], bfr[NI];
        #pragma unroll
        for (int i = 0; i < NI; i++) {
            af[i]  = *(const bf16x8*)&rA[(wm + i * 16 + lrow) * BK + pc0];
            bfr[i] = *(const bf16x8*)&rB[(wn + i * 16 + lrow) * BK + pc0];
        }
        #pragma unroll
        for (int i = 0; i < NI; i++)
            #pragma unroll
            for (int j = 0; j < NI; j++)
                acc[i][j] = __builtin_amdgcn_mfma_f32_16x16x32_bf16(af[i], bfr[j], acc[i][j], 0, 0, 0);
        #pragma unroll
        for (int i = 0; i < NI; i++) {
            af[i]  = *(const bf16x8*)&rA[(wm + i * 16 + lrow) * BK + pc1];
            bfr[i] = *(const bf16x8*)&rB[(wn + i * 16 + lrow) * BK + pc1];
        }
        #pragma unroll
        for (int i = 0; i < NI; i++)
            #pragma unroll
            for (int j = 0; j < NI; j++)
                acc[i][j] = __builtin_amdgcn_mfma_f32_16x16x32_bf16(af[i], bfr[j], acc[i][j], 0, 0, 0);

        __syncthreads();   // drains prefetch (vmcnt) + readers (lgkm); swap
        cur ^= 1;
    }

    const int oF32 = (outKind == 1) | ((outKind == 2) & dt);
    // C/D layout (m89-verified): col = lane&15, row = quad*4 + reg
    #pragma unroll
    for (int i = 0; i < NI; i++) {
        const int mr = m0 + wm + i * 16 + quad * 4;
        #pragma unroll
        for (int j = 0; j < NI; j++) {
            const int nc = n0 + wn + j * 16 + lrow;
            #pragma unroll
            for (int r = 0; r < 4; r++) {
                const long ofs = cBase + (long)(mr + r) * ldc + nc;
                const float v = acc[i][j][r] * scale;
                if (oF32) ((float*)Call)[ofs] = v;
                else      ((unsigned short*)Call)[ofs] = f2bf(v);
            }
        }
    }
}

// One-pass cast/transpose (fallback path only).
__global__ __launch_bounds__(256)
void xpose_cast(const void* __restrict__ src, unsigned short* __restrict__ dT,
                unsigned short* __restrict__ dC, int R, int C,
                long oS, long sS, long sDT, long sDC,
                const int* __restrict__ dtf, int srcExt)
{
    const int dt = srcExt ? *dtf : 0;
    const int b = blockIdx.z;
    const long sb = oS + (long)b * sS;
    __shared__ unsigned short t[64][65];
    const int c0 = blockIdx.x * 64, r0 = blockIdx.y * 64;
    const int tid = threadIdx.x;
    #pragma unroll
    for (int it = 0; it < 16; it++) {
        int idx = it * 256 + tid;
        int r = idx >> 6, c = idx & 63;
        long e = sb + (long)(r0 + r) * C + (c0 + c);
        unsigned short v = dt ? f2bf(((const float*)src)[e]) : ((const unsigned short*)src)[e];
        t[r][c] = v;
        if (dC) dC[(long)b * sDC + (long)(r0 + r) * C + (c0 + c)] = v;
    }
    if (!dT) return;
    __syncthreads();
    #pragma unroll
    for (int it = 0; it < 16; it++) {
        int idx = it * 256 + tid;
        int r = idx >> 6, c = idx & 63;
        dT[(long)b * sDT + (long)(c0 + r) * R + (r0 + c)] = t[c][r];
    }
}

// fp32-Sc softmax (fallback path): row softmaxed in place as bf16 P in the
// first half of its fp32 row (P lda = 2S).
__global__ __launch_bounds__(256)
void softmax_causal(float* __restrict__ Sc, int S, int CH, int q0)
{
    const int r = blockIdx.x, z = blockIdx.y;
    float* srow = Sc + ((long)z * CH + r) * S;
    unsigned short* prow = (unsigned short*)srow;
    const int n = q0 + r + 1;
    const int limit = q0 + (r & ~127) + 128;   // tile-aligned causal bound
    const int tid = threadIdx.x;
    const int lane = tid & 63, wave = tid >> 6;
    const int j0 = tid * 8;
    __shared__ float red[4];

    float v[8];
    {
        f32x4 a = *(const f32x4*)(srow + j0);
        f32x4 b = *(const f32x4*)(srow + j0 + 4);
        #pragma unroll
        for (int c = 0; c < 4; c++) { v[c] = a[c]; v[4 + c] = b[c]; }
    }
    float lm = -1e30f;
    #pragma unroll
    for (int c = 0; c < 8; c++) {
        v[c] = (j0 + c < n) ? v[c] : -1e30f;
        lm = fmaxf(lm, v[c]);
    }
    #pragma unroll
    for (int o = 32; o >= 1; o >>= 1) lm = fmaxf(lm, __shfl_xor(lm, o, 64));
    if (lane == 0) red[wave] = lm;
    __syncthreads();
    const float m = fmaxf(fmaxf(red[0], red[1]), fmaxf(red[2], red[3]));
    __syncthreads();

    float ev[8];
    float ls = 0.f;
    #pragma unroll
    for (int c = 0; c < 8; c++) {
        float e = (j0 + c < n) ? __expf(v[c] - m) : 0.f;
        ev[c] = e;
        ls += e;
    }
    #pragma unroll
    for (int o = 32; o >= 1; o >>= 1) ls += __shfl_xor(ls, o, 64);
    if (lane == 0) red[wave] = ls;
    __syncthreads();   // all fp32 reads done before aliasing bf16 writes
    const float inv = 1.0f / (red[0] + red[1] + red[2] + red[3]);

    if (j0 < limit) {
        union { short8 s; unsigned short u[8]; } o;
        #pragma unroll
        for (int c = 0; c < 8; c++) o.u[c] = f2bf(ev[c] * inv);
        *(short8*)(prow + j0) = o.s;
    }
}

// bf16-Sc softmax (Config A+): Sc [ZB][CH][S] bf16, row softmaxed IN PLACE
// (P lda = S). Causal read-guard: threads with j0 >= limit never touch memory
// (Sc beyond limit is unwritten garbage — never read, never written).
// Each thread owns its 8 elems; no cross-thread aliasing -> no extra sync.
__global__ __launch_bounds__(256)
void softmax_causal_b16(unsigned short* __restrict__ Sc, int S, int CH, int q0)
{
    const int r = blockIdx.x, z = blockIdx.y;
    unsigned short* row = Sc + ((long)z * CH + r) * S;
    const int n = q0 + r + 1;
    const int limit = q0 + (r & ~127) + 128;   // tile-aligned causal bound >= n
    const int tid = threadIdx.x;
    const int lane = tid & 63, wave = tid >> 6;
    const int j0 = tid * 8;
    __shared__ float red[4];

    float v[8];
    if (j0 < limit) {   // limit%128==0, j0%8==0 -> whole 8-vector in-bounds
        union { short8 s; unsigned short u[8]; } in;
        in.s = *(const short8*)(row + j0);
        #pragma unroll
        for (int c = 0; c < 8; c++) {
            union { unsigned u; float f; } w; w.u = (unsigned)in.u[c] << 16;
            v[c] = (j0 + c < n) ? w.f : -1e30f;
        }
    } else {
        #pragma unroll
        for (int c = 0; c < 8; c++) v[c] = -1e30f;
    }
    float lm = -1e30f;
    #pragma unroll
    for (int c = 0; c < 8; c++) lm = fmaxf(lm, v[c]);
    #pragma unroll
    for (int o = 32; o >= 1; o >>= 1) lm = fmaxf(lm, __shfl_xor(lm, o, 64));
    if (lane == 0) red[wave] = lm;
    __syncthreads();
    const float m = fmaxf(fmaxf(red[0], red[1]), fmaxf(red[2], red[3]));
    __syncthreads();

    float ev[8];
    float ls = 0.f;
    #pragma unroll
    for (int c = 0; c < 8; c++) {
        float e = (j0 + c < n) ? __expf(v[c] - m) : 0.f;
        ev[c] = e;
        ls += e;
    }
    #pragma unroll
    for (int o = 32; o >= 1; o >>= 1) ls += __shfl_xor(ls, o, 64);
    if (lane == 0) red[wave] = ls;
    __syncthreads();
    const float inv = 1.0f / (red[0] + red[1] + red[2] + red[3]);

    if (j0 < limit) {
        union { short8 s; unsigned short u[8]; } o;
        #pragma unroll
        for (int c = 0; c < 8; c++) o.u[c] = f2bf(ev[c] * inv);
        *(short8*)(row + j0) = o.s;
    }
}

__global__ __launch_bounds__(256)
void fill_zero(void* o, long n, const int* dtf)
{
    long i = (long)blockIdx.x * 256 + threadIdx.x;
    if (i < n) {
        if (*dtf) ((float*)o)[i] = 0.f;
        else ((unsigned short*)o)[i] = 0;
    }
}

extern "C" void kernel_launch(void* const* d_in, const int* in_sizes, int n_in,
                              void* d_out, int out_size, void* d_ws, size_t ws_size,
                              hipStream_t stream)
{
    const int B = 4, S = 2048, D = 1024;
    const void* x  = d_in[0];
    const void* Qw = d_in[1];
    const void* Kw = d_in[2];
    const void* Vw = d_in[3];
    (void)in_sizes; (void)n_in; (void)out_size;

    // scores = X (Qw Kw^T) X^T / 32 ; out = P (X Vw).
    //   prep -> WT = Kw@Qw^T/32 -> fused{G = Xb@WT^T, VbT = VwT@Xb^T}
    //   -> Sc = G@Xb^T (causal, bf16) -> softmax_b16 in place -> out = P@VbT^T
    int* dtf = (int*)d_ws;
    char* p = (char*)d_ws + 4096;
    const size_t MB = (size_t)1 << 20;
    const unsigned short* nullB = nullptr;

    const long nOut = (long)B * S * D;
    const long nX = (long)B * S * D;
    const long nW = (long)D * D;
    const int prepBlocks = (int)(nX >> 11) + 2 * (int)(nW >> 11) + (D / 64) * (D / 64);

    // ---- Config A+: bf16 Sc (84MB+4KB).
    // ws: dtf | QwB 2MB | KwB 2MB | Xb 16MB | Buf 16MB (G) | VbT 16MB |
    //     Sc bf16 32MB (WT in first 2MB, VwT in next 2MB — both consumed by
    //     the fused GEMM before the Sc GEMM overwrites them).
    const size_t needAp = 4096 + 52 * MB + (size_t)B * S * S * 2;
    if (ws_size >= needAp) {
        unsigned short* QwB = (unsigned short*)p;
        unsigned short* KwB = (unsigned short*)(p + 2 * MB);
        unsigned short* Xb  = (unsigned short*)(p + 4 * MB);
        unsigned short* Buf = (unsigned short*)(p + 20 * MB);
        unsigned short* VbT = (unsigned short*)(p + 36 * MB);
        unsigned short* Sc  = (unsigned short*)(p + 52 * MB);
        unsigned short* WT  = Sc;                              // Sc head
        unsigned short* VwT = (unsigned short*)((char*)Sc + 2 * MB);

        prep<<<dim3(prepBlocks), 256, 0, stream>>>(
            x, Qw, Kw, Vw, Xb, QwB, KwB, VwT, nX, nW, D, dtf);
        // WT = Kw @ Qw^T / 32   [256 blocks]
        gemm_bt<64><<<dim3(16, 16, 1), 256, 0, stream>>>(
            KwB, QwB, WT, D, D, D, D, 0L, 0L, 0L, 0L, 0L, 0L,
            0.03125f, 0, 0, dtf, 0, nullB, nullptr, nullB, 0);
        // fused: G = Xb@WT^T -> Buf  |  VbT = VwT@Xb^T -> VbT   [1024 blocks]
        gemm_bt<128><<<dim3(1024, 1, 1), 256, 0, stream>>>(
            Xb, WT, Buf, D, D, D, D,
            0L, 0L, 0L, 0L, (long)S * D, (long)D * S,
            1.0f, 4, 0, dtf, 0, Xb, VbT, VwT, S);
        // Sc = G @ Xb^T  (causal tiles, bf16 out)   [544 blocks]
        gemm_bt<128><<<dim3(136, 1, 4), 256, 0, stream>>>(
            Buf, Xb, Sc, D, D, D, S,
            0L, 0L, 0L, (long)S * D, (long)S * D, (long)S * S,
            1.0f, 1, 0, dtf, 0, nullB, nullptr, nullB, 0);
        softmax_causal_b16<<<dim3(S, 4), 256, 0, stream>>>(Sc, S, S, 0);
        // out = P @ VbT^T (mode 3, distance-256 balance)   [512 blocks]
        gemm_bt<128><<<dim3(512, 1, 1), 256, 0, stream>>>(
            Sc, VbT, d_out, S, S, S, D,
            0L, 0L, 0L, (long)S * S, (long)D * S, (long)S * D,
            1.0f, 3, 0, dtf, 2, nullB, nullptr, nullB, 0);
        return;
    }

    // ---- Config A: r11 structure (100MB+4KB) — z-form dual + xpose + fp32 Sc.
    const size_t needA = 4096 + 36 * MB + (size_t)B * S * S * 4;
    if (ws_size >= needA) {
        unsigned short* QwB = (unsigned short*)p;
        unsigned short* KwB = (unsigned short*)(p + 2 * MB);
        unsigned short* Xb  = (unsigned short*)(p + 4 * MB);
        unsigned short* Buf = (unsigned short*)(p + 20 * MB);
        float* Sc = (float*)(p + 36 * MB);
        unsigned short* WT  = (unsigned short*)Sc;            // Sc head
        unsigned short* VwT = (unsigned short*)((char*)Sc + 2 * MB);
        unsigned short* VbT = Xb;                             // Xb dead after Sc
        unsigned short* VbS = (unsigned short*)d_out;         // Vb scratch

        prep<<<dim3(prepBlocks), 256, 0, stream>>>(
            x, Qw, Kw, Vw, Xb, QwB, KwB, VwT, nX, nW, D, dtf);
        gemm_bt<64><<<dim3(16, 16, 1), 256, 0, stream>>>(
            KwB, QwB, WT, D, D, D, D, 0L, 0L, 0L, 0L, 0L, 0L,
            0.03125f, 0, 0, dtf, 0, nullB, nullptr, nullB, 0);
        gemm_bt<128><<<dim3(8, 64, 2), 256, 0, stream>>>(
            Xb, WT, Buf, D, D, D, D, 0L, 0L, 0L, 0L, 0L, 0L,
            1.0f, 0, 0, dtf, 0, VwT, VbS, nullB, 0);
        gemm_bt<128><<<dim3(136, 1, 4), 256, 0, stream>>>(
            Buf, Xb, (void*)Sc, D, D, D, S,
            0L, 0L, 0L, (long)S * D, (long)S * D, (long)S * S,
            1.0f, 1, 0, dtf, 1, nullB, nullptr, nullB, 0);
        softmax_causal<<<dim3(S, 4), 256, 0, stream>>>(Sc, S, S, 0);
        xpose_cast<<<dim3(16, 32, 4), 256, 0, stream>>>(
            VbS, VbT, nullptr, S, D, 0L, (long)S * D, (long)D * S, 0L, dtf, 0);
        gemm_bt<128><<<dim3(512, 1, 1), 256, 0, stream>>>(
            (const unsigned short*)Sc, VbT, d_out, S, 2 * S, S, D,
            0L, 0L, 0L, (long)2 * S * S, (long)D * S, (long)S * D,
            1.0f, 3, 0, dtf, 2, nullB, nullptr, nullB, 0);
        return;
    }

    // ---- Generic chunked fallback: fixed = 56MB + Sc chunk (fp32).
    const int cfgs[6][2] = {{4,1024},{2,1024},{1,1024},{1,512},{1,256},{1,128}};
    int ZB = 0, CH = 0;
    for (int i = 0; i < 6; i++) {
        size_t need = 4096 + 56 * MB + (size_t)cfgs[i][0] * cfgs[i][1] * S * 4;
        if (need <= ws_size) { ZB = cfgs[i][0]; CH = cfgs[i][1]; break; }
    }
    if (ZB == 0) {  // diagnostic zeros
        detect_dtype<<<1, 256, 0, stream>>>((const unsigned short*)x, dtf);
        fill_zero<<<dim3((unsigned)((nOut + 255) / 256)), 256, 0, stream>>>(d_out, nOut, dtf);
        return;
    }

    unsigned short* QwB = (unsigned short*)p;
    unsigned short* KwB = (unsigned short*)(p + 2 * MB);
    unsigned short* WT  = (unsigned short*)(p + 4 * MB);
    unsigned short* VwT = (unsigned short*)(p + 6 * MB);
    unsigned short* Xb  = (unsigned short*)(p + 8 * MB);
    unsigned short* VbT = (unsigned short*)(p + 24 * MB);
    unsigned short* Buf = (unsigned short*)(p + 40 * MB);
    float* Sc = (float*)(p + 56 * MB);
    unsigned short* VbS = (unsigned short*)d_out;   // Vb scratch (dead pre-out)

    prep<<<dim3(prepBlocks), 256, 0, stream>>>(
        x, Qw, Kw, Vw, Xb, QwB, KwB, VwT, nX, nW, D, dtf);
    gemm_bt<64><<<dim3(16, 16, 1), 256, 0, stream>>>(
        KwB, QwB, WT, D, D, D, D, 0L, 0L, 0L, 0L, 0L, 0L,
        0.03125f, 0, 0, dtf, 0, nullB, nullptr, nullB, 0);
    gemm_bt<128><<<dim3(8, 64, 2), 256, 0, stream>>>(
        Xb, WT, Buf, D, D, D, D, 0L, 0L, 0L, 0L, 0L, 0L,
        1.0f, 0, 0, dtf, 0, VwT, VbS, nullB, 0);
    xpose_cast<<<dim3(16, 32, 4), 256, 0, stream>>>(
        VbS, VbT, nullptr, S, D, 0L, (long)S * D, (long)D * S, 0L, dtf, 0);

    for (int b0 = 0; b0 < B; b0 += ZB) {
        for (int q0 = 0; q0 < S; q0 += CH) {
            const int base = q0 / 128, R = CH / 128;
            const int ntiles = R * (base + 1) + R * (R - 1) / 2;

            gemm_bt<128><<<dim3(ntiles, 1, ZB), 256, 0, stream>>>(
                Buf, Xb, (void*)Sc, D, D, D, S,
                (long)b0 * S * D + (long)q0 * D, (long)b0 * S * D, 0L,
                (long)S * D, (long)S * D, (long)CH * S,
                1.0f, 1, q0, dtf, 1, nullB, nullptr, nullB, 0);

            softmax_causal<<<dim3(CH, ZB), 256, 0, stream>>>(Sc, S, CH, q0);

            gemm_bt<128><<<dim3(8, CH / 128, ZB), 256, 0, stream>>>(
                (const unsigned short*)Sc, VbT, d_out, S, 2 * S, S, D,
                0L, (long)b0 * D * S, (long)b0 * S * D + (long)q0 * D,
                (long)CH * 2 * S, (long)D * S, (long)S * D,
                1.0f, 2, q0, dtf, 2, nullB, nullptr, nullB, 0);
        }
    }
}

// Round 14
// 244.722 us; speedup vs baseline: 1.0564x; 1.0137x over previous
//
// Self-attention (B=4,S=2048,D=1024) via W-fused GEMM pipeline.
#include <hip/hip_runtime.h>
#include <hip/hip_bf16.h>

typedef __attribute__((ext_vector_type(8))) __bf16 bf16x8;
typedef __attribute__((ext_vector_type(8))) short short8;
typedef __attribute__((ext_vector_type(4))) float f32x4;

#define BK 64
// TM x TM tiles (128 main, 64 WT), BK=64, dbuf 2-phase (proven r2/5/9).
// r6: BK=32 regression. LDS 64KB -> 2 blocks/CU. Bank swizzle (rule #21/m173):
// col16 c of row r at phys slot c^(r&7); staging lane l fetches global col16
// (l&7)^(l>>3); ds_read uses q^(lrow&7). SQ_LDS_BANK_CONFLICT = 0 (r2..r13).
// r10: paired dual thrashed L2 -> z-form. r11: mode-3 distance-256 balance.
// r12: VbT direct GEMM. r13: bf16 Sc + fused G/VbT (51.3us, 2.0 rounds).
// r14: regroup — G alone (1.0 round) + fused Sc+VbT (mode 5, 1056 blocks =
// 2.06 rounds): Sc's half-empty tail round (r12: 544 blocks stretched 1.06 ->
// ~1.7 rounds) is back-filled with VbT work. WT/VwT moved OUT of the Sc
// region (Sc-writes race VbT's VwT-reads otherwise).

__device__ inline unsigned short f2bf(float f) {  // RNE fp32->bf16
    union { float f; unsigned u; } v; v.f = f;
    unsigned r = (v.u + 0x7FFFu + ((v.u >> 16) & 1u)) >> 16;
    return (unsigned short)r;
}

// async global->LDS, 16B per lane. g: per-lane global addr; l: wave-uniform LDS base.
__device__ __forceinline__ void gld16(const void* g, void* l) {
    __builtin_amdgcn_global_load_lds(
        (const __attribute__((address_space(1))) unsigned int*)g,
        (__attribute__((address_space(3))) unsigned int*)l, 16, 0, 0);
}

// dtype probe core: even ushorts of bf16 N(0,1) data have sane exponents
// (~100% in [0x60,0x88]); of fp32 data they are uniform mantissa bits (~16%).
__device__ inline int detect_dt(const unsigned short* x, int tid, int* red)
{
    int cnt = 0;
    for (int i = tid; i < 1024; i += 256) {
        unsigned e = (x[2 * i] >> 7) & 0xFFu;
        cnt += (e >= 0x60u && e <= 0x88u) ? 1 : 0;
    }
    #pragma unroll
    for (int o = 32; o >= 1; o >>= 1) cnt += __shfl_xor(cnt, o, 64);
    if ((tid & 63) == 0) red[tid >> 6] = cnt;
    __syncthreads();
    return (red[0] + red[1] + red[2] + red[3] >= 512) ? 0 : 1;
}

__global__ void detect_dtype(const unsigned short* __restrict__ x, int* __restrict__ flag)
{
    __shared__ int red[4];
    const int dt = detect_dt(x, threadIdx.x, red);
    if (threadIdx.x == 0) *flag = dt;
}

// All input prep in ONE launch (flat grid, range-dispatched). Each block
// self-detects dtype (deterministic -> uniform); block 0 publishes dtf.
//   [0, nbX)            : Xb  = bf16(x)
//   [nbX, nbX+nbW)      : QwB = bf16(Qw)
//   [nbX+nbW, nbX+2nbW) : KwB = bf16(Kw)
//   [nbX+2nbW, +256)    : VwT = bf16(Vw)^T  64x64 LDS-tile transpose
__global__ __launch_bounds__(256)
void prep(const void* __restrict__ x, const void* __restrict__ Qw,
          const void* __restrict__ Kw, const void* __restrict__ Vw,
          unsigned short* __restrict__ Xb, unsigned short* __restrict__ QwB,
          unsigned short* __restrict__ KwB, unsigned short* __restrict__ VwT,
          long nX, long nW, int Dd, int* __restrict__ dtf)
{
    const int bid = blockIdx.x;
    const int tid = threadIdx.x;
    __shared__ int red[4];
    const int dt = detect_dt((const unsigned short*)x, tid, red);
    if (bid == 0 && tid == 0) *dtf = dt;

    const int nbX = (int)(nX >> 11);   // 2048 elems per copy block
    const int nbW = (int)(nW >> 11);
    __shared__ unsigned short tbuf[64][65];

    if (bid < nbX + 2 * nbW) {
        const void* s; unsigned short* d; long i;
        if (bid < nbX)            { s = x;  d = Xb;  i = ((long)bid << 11) + tid * 8; }
        else if (bid < nbX + nbW) { s = Qw; d = QwB; i = ((long)(bid - nbX) << 11) + tid * 8; }
        else                      { s = Kw; d = KwB; i = ((long)(bid - nbX - nbW) << 11) + tid * 8; }
        union { short8 v; unsigned short u[8]; } o;
        if (dt) {
            f32x4 a = *(const f32x4*)((const float*)s + i);
            f32x4 b = *(const f32x4*)((const float*)s + i + 4);
            #pragma unroll
            for (int j = 0; j < 4; j++) { o.u[j] = f2bf(a[j]); o.u[4 + j] = f2bf(b[j]); }
        } else {
            o.v = *(const short8*)((const short*)s + i);
        }
        *(short8*)(d + i) = o.v;
        return;
    }
    const int t64 = bid - (nbX + 2 * nbW);          // 0..(Dd/64)^2-1
    const int c0 = (t64 & 15) * 64, r0 = (t64 >> 4) * 64;
    #pragma unroll
    for (int it = 0; it < 16; it++) {
        int idx = it * 256 + tid;
        int r = idx >> 6, c = idx & 63;
        long e = (long)(r0 + r) * Dd + (c0 + c);
        tbuf[r][c] = dt ? f2bf(((const float*)Vw)[e]) : ((const unsigned short*)Vw)[e];
    }
    __syncthreads();
    #pragma unroll
    for (int it = 0; it < 16; it++) {
        int idx = it * 256 + tid;
        int r = idx >> 6, c = idx & 63;
        VwT[(long)(c0 + r) * Dd + (r0 + c)] = tbuf[c][r];
    }
}

// C = A @ Bt^T, all operands bf16. A [M][K] (lda), Bt [N][K] (ldb);
// offsets/strides in ELEMENTS. outKind: 0 bf16, 1 fp32, 2 external-dtype.
// mode 0: plain (XCD remap); z-form dual-B if Bt2 != null.
// mode 1: enumerated causal tiles (triangle decode, blockIdx.z = z).
// mode 2: causal k-limit, adjacent-id pairing (fallback path).
// mode 3: causal k-limit, distance-256 complementary pairing, flat 512 grid
//   (assumes 16mt x 8nt x 4z, q0=0).
// mode 5: FUSED Sc+VbT over flat 1056 grid (all jobs full-K, uniform work):
//   remapped lin < 544 -> Sc causal tile (z=lin/136, triangle decode of
//   lin%136; A,Bt,Call,ldc; bases via sA/sB/sC);
//   lin >= 544 -> VbT tile (j2=lin-544: z=j2>>7, mt=(j2&127)>>4, nt=j2&15;
//   A=A2 (no batch), Bt with bBase=z*sB, C=C2 with ldc=ldc2,
//   cBase=z*K*ldc2).
template <int TM>
__global__ __launch_bounds__(256, 2)
void gemm_bt(const unsigned short* __restrict__ A, const unsigned short* __restrict__ Bt,
             void* __restrict__ Call, int K, int lda, int ldb, int ldc,
             long oA, long oB, long oC, long sA, long sB, long sC,
             float scale, int mode, int q0,
             const int* __restrict__ dtf, int outKind,
             const unsigned short* __restrict__ Bt2, void* __restrict__ C2,
             const unsigned short* __restrict__ A2, int ldc2)
{
    constexpr int NI = TM / 32;           // 16x16 frags per wave dim
    const int dt = *dtf;
    int zSel = blockIdx.z;
    int isVb = 0;
    if (mode == 0 && Bt2 && zSel) { Bt = Bt2; Call = C2; }   // z-form dual

    int mt, nt;
    if (mode == 5) {
        int lin = blockIdx.x;                        // 1056 blocks
        const int xcd = lin & 7, idx = lin >> 3;
        lin = xcd * 132 + idx;                       // bijective (1056 = 8*132)
        if (lin < 544) {                             // Sc causal triangle
            zSel = lin / 136;
            int rem = lin - zSel * 136, rr = 0, w = 1;
            while (rem >= w) { rem -= w; rr++; w++; }
            mt = rr; nt = rem;
        } else {                                     // VbT direct
            const int j2 = lin - 544;
            zSel = j2 >> 7;
            const int r2 = j2 & 127;
            mt = r2 >> 4; nt = r2 & 15;
            A = A2; Call = C2; ldc = ldc2;
            isVb = 1;
        }
    } else if (mode == 3) {
        const int lin = blockIdx.x;                  // 512 blocks
        const int j = (lin < 256) ? lin : 767 - lin; // kmax-desc job index
        mt = 15 - (j >> 5);                          // j=0 -> heaviest (mt=15)
        zSel = (j >> 3) & 3;
        nt = j & 7;
    } else if (mode == 2) {
        const int nwg2 = gridDim.x * gridDim.y;
        const int h = blockIdx.y * gridDim.x + blockIdx.x;
        const int u = h >> 1;
        const int rank = (h & 1) ? (nwg2 - 1 - u) : u;   // 0 = heaviest
        mt = (gridDim.y - 1) - (rank / (int)gridDim.x);
        nt = rank % (int)gridDim.x;
    } else {
        // XCD-aware bijective remap (T1, m204 formula).
        const int nwg = gridDim.x * gridDim.y;
        int lin = blockIdx.y * gridDim.x + blockIdx.x;
        const int q = nwg >> 3, r = nwg & 7;
        const int xcd = lin & 7, idx = lin >> 3;
        lin = (xcd < r ? xcd * (q + 1) : r * (q + 1) + (xcd - r) * q) + idx;
        if (mode == 1) {  // decode linear id over the causal tile triangle
            int rem = lin, rr = 0, w = q0 / TM + 1;
            while (rem >= w) { rem -= w; rr++; w++; }
            mt = rr; nt = rem;
        } else { mt = lin / gridDim.x; nt = lin % gridDim.x; }
    }
    const long aBase = isVb ? 0L : (oA + (long)zSel * sA);
    const long bBase = oB + (long)zSel * sB;
    const long cBase = isVb ? ((long)zSel * (long)K * ldc)
                            : (oC + (long)zSel * sC);
    const int m0 = mt * TM;
    const int n0 = nt * TM;
    int kmax = K;
    if (mode == 2 || mode == 3) kmax = min(K, q0 + m0 + TM);

    __shared__ __align__(16) short As[2][TM * BK];
    __shared__ __align__(16) short Bs[2][TM * BK];

    const int tid  = threadIdx.x;
    const int wave = tid >> 6;
    const int lane = tid & 63;
    const int wm = (wave >> 1) * (TM / 2);
    const int wn = (wave & 1) * (TM / 2);
    const int lrow = lane & 15;
    const int quad = lane >> 4;

    // Staging: per wave TM/4 rows of A and of B per K-step, in 8-row/1KB gld16
    // chunks. lane l -> chunk row l>>3, pre-swizzled global col16 (l&7)^(l>>3).
    const int sRow = lane >> 3;
    const int sCol = ((lane & 7) ^ sRow) * 8;  // elements
    const long gA = aBase + (long)(m0 + wave * (TM / 4) + sRow) * lda + sCol;
    const long gB = bBase + (long)(n0 + wave * (TM / 4) + sRow) * ldb + sCol;

    auto stage = [&](int buf, int k0) {
        short* dA = &As[buf][wave * (TM / 4) * BK];
        short* dB = &Bs[buf][wave * (TM / 4) * BK];
        const unsigned short* pA = A + gA + k0;
        const unsigned short* pB = Bt + gB + k0;
        #pragma unroll
        for (int c = 0; c < TM / 32; c++) {
            gld16(pA + (long)(c * 8) * lda, dA + c * 8 * BK);
            gld16(pB + (long)(c * 8) * ldb, dB + c * 8 * BK);
        }
    };

    f32x4 acc[NI][NI];
    #pragma unroll
    for (int i = 0; i < NI; i++)
        #pragma unroll
        for (int j = 0; j < NI; j++) {
            f32x4 zero = {0.f, 0.f, 0.f, 0.f};
            acc[i][j] = zero;
        }

    // ds_read physical col16 slots for the two K-halves (lane-constant:
    // row = wm + i*16 + lrow, and wm/i*16 are multiples of 8 -> row&7 == lrow&7).
    const int rq  = lrow & 7;
    const int pc0 = (quad ^ rq) * 8;
    const int pc1 = ((quad + 4) ^ rq) * 8;

    stage(0, 0);
    __syncthreads();    // vmcnt(0) drained before barrier -> tile 0 ready
    int cur = 0;

    for (int k0 = 0; k0 < kmax; k0 += BK) {
        const int kn = k0 + BK;
        if (kn < kmax) stage(cur ^ 1, kn);   // prefetch in flight during compute

        const short* rA = &As[cur][0];
        const short* rB = &Bs[cur][0];
        bf16x8 af[NI], bfr[NI];
        #pragma unroll
        for (int i = 0; i < NI; i++) {
            af[i]  = *(const bf16x8*)&rA[(wm + i * 16 + lrow) * BK + pc0];
            bfr[i] = *(const bf16x8*)&rB[(wn + i * 16 + lrow) * BK + pc0];
        }
        #pragma unroll
        for (int i = 0; i < NI; i++)
            #pragma unroll
            for (int j = 0; j < NI; j++)
                acc[i][j] = __builtin_amdgcn_mfma_f32_16x16x32_bf16(af[i], bfr[j], acc[i][j], 0, 0, 0);
        #pragma unroll
        for (int i = 0; i < NI; i++) {
            af[i]  = *(const bf16x8*)&rA[(wm + i * 16 + lrow) * BK + pc1];
            bfr[i] = *(const bf16x8*)&rB[(wn + i * 16 + lrow) * BK + pc1];
        }
        #pragma unroll
        for (int i = 0; i < NI; i++)
            #pragma unroll
            for (int j = 0; j < NI; j++)
                acc[i][j] = __builtin_amdgcn_mfma_f32_16x16x32_bf16(af[i], bfr[j], acc[i][j], 0, 0, 0);

        __syncthreads();   // drains prefetch (vmcnt) + readers (lgkm); swap
        cur ^= 1;
    }

    const int oF32 = (outKind == 1) | ((outKind == 2) & dt);
    // C/D layout (m89-verified): col = lane&15, row = quad*4 + reg
    #pragma unroll
    for (int i = 0; i < NI; i++) {
        const int mr = m0 + wm + i * 16 + quad * 4;
        #pragma unroll
        for (int j = 0; j < NI; j++) {
            const int nc = n0 + wn + j * 16 + lrow;
            #pragma unroll
            for (int r = 0; r < 4; r++) {
                const long ofs = cBase + (long)(mr + r) * ldc + nc;
                const float v = acc[i][j][r] * scale;
                if (oF32) ((float*)Call)[ofs] = v;
                else      ((unsigned short*)Call)[ofs] = f2bf(v);
            }
        }
    }
}

// One-pass cast/transpose (fallback path only).
__global__ __launch_bounds__(256)
void xpose_cast(const void* __restrict__ src, unsigned short* __restrict__ dT,
                unsigned short* __restrict__ dC, int R, int C,
                long oS, long sS, long sDT, long sDC,
                const int* __restrict__ dtf, int srcExt)
{
    const int dt = srcExt ? *dtf : 0;
    const int b = blockIdx.z;
    const long sb = oS + (long)b * sS;
    __shared__ unsigned short t[64][65];
    const int c0 = blockIdx.x * 64, r0 = blockIdx.y * 64;
    const int tid = threadIdx.x;
    #pragma unroll
    for (int it = 0; it < 16; it++) {
        int idx = it * 256 + tid;
        int r = idx >> 6, c = idx & 63;
        long e = sb + (long)(r0 + r) * C + (c0 + c);
        unsigned short v = dt ? f2bf(((const float*)src)[e]) : ((const unsigned short*)src)[e];
        t[r][c] = v;
        if (dC) dC[(long)b * sDC + (long)(r0 + r) * C + (c0 + c)] = v;
    }
    if (!dT) return;
    __syncthreads();
    #pragma unroll
    for (int it = 0; it < 16; it++) {
        int idx = it * 256 + tid;
        int r = idx >> 6, c = idx & 63;
        dT[(long)b * sDT + (long)(c0 + r) * R + (r0 + c)] = t[c][r];
    }
}

// fp32-Sc softmax (fallback path): row softmaxed in place as bf16 P in the
// first half of its fp32 row (P lda = 2S).
__global__ __launch_bounds__(256)
void softmax_causal(float* __restrict__ Sc, int S, int CH, int q0)
{
    const int r = blockIdx.x, z = blockIdx.y;
    float* srow = Sc + ((long)z * CH + r) * S;
    unsigned short* prow = (unsigned short*)srow;
    const int n = q0 + r + 1;
    const int limit = q0 + (r & ~127) + 128;   // tile-aligned causal bound
    const int tid = threadIdx.x;
    const int lane = tid & 63, wave = tid >> 6;
    const int j0 = tid * 8;
    __shared__ float red[4];

    float v[8];
    {
        f32x4 a = *(const f32x4*)(srow + j0);
        f32x4 b = *(const f32x4*)(srow + j0 + 4);
        #pragma unroll
        for (int c = 0; c < 4; c++) { v[c] = a[c]; v[4 + c] = b[c]; }
    }
    float lm = -1e30f;
    #pragma unroll
    for (int c = 0; c < 8; c++) {
        v[c] = (j0 + c < n) ? v[c] : -1e30f;
        lm = fmaxf(lm, v[c]);
    }
    #pragma unroll
    for (int o = 32; o >= 1; o >>= 1) lm = fmaxf(lm, __shfl_xor(lm, o, 64));
    if (lane == 0) red[wave] = lm;
    __syncthreads();
    const float m = fmaxf(fmaxf(red[0], red[1]), fmaxf(red[2], red[3]));
    __syncthreads();

    float ev[8];
    float ls = 0.f;
    #pragma unroll
    for (int c = 0; c < 8; c++) {
        float e = (j0 + c < n) ? __expf(v[c] - m) : 0.f;
        ev[c] = e;
        ls += e;
    }
    #pragma unroll
    for (int o = 32; o >= 1; o >>= 1) ls += __shfl_xor(ls, o, 64);
    if (lane == 0) red[wave] = ls;
    __syncthreads();   // all fp32 reads done before aliasing bf16 writes
    const float inv = 1.0f / (red[0] + red[1] + red[2] + red[3]);

    if (j0 < limit) {
        union { short8 s; unsigned short u[8]; } o;
        #pragma unroll
        for (int c = 0; c < 8; c++) o.u[c] = f2bf(ev[c] * inv);
        *(short8*)(prow + j0) = o.s;
    }
}

// bf16-Sc softmax (Config A+): Sc [ZB][CH][S] bf16, row softmaxed IN PLACE
// (P lda = S). Causal read-guard: threads with j0 >= limit never touch memory.
__global__ __launch_bounds__(256)
void softmax_causal_b16(unsigned short* __restrict__ Sc, int S, int CH, int q0)
{
    const int r = blockIdx.x, z = blockIdx.y;
    unsigned short* row = Sc + ((long)z * CH + r) * S;
    const int n = q0 + r + 1;
    const int limit = q0 + (r & ~127) + 128;   // tile-aligned causal bound >= n
    const int tid = threadIdx.x;
    const int lane = tid & 63, wave = tid >> 6;
    const int j0 = tid * 8;
    __shared__ float red[4];

    float v[8];
    if (j0 < limit) {   // limit%128==0, j0%8==0 -> whole 8-vector in-bounds
        union { short8 s; unsigned short u[8]; } in;
        in.s = *(const short8*)(row + j0);
        #pragma unroll
        for (int c = 0; c < 8; c++) {
            union { unsigned u; float f; } w; w.u = (unsigned)in.u[c] << 16;
            v[c] = (j0 + c < n) ? w.f : -1e30f;
        }
    } else {
        #pragma unroll
        for (int c = 0; c < 8; c++) v[c] = -1e30f;
    }
    float lm = -1e30f;
    #pragma unroll
    for (int c = 0; c < 8; c++) lm = fmaxf(lm, v[c]);
    #pragma unroll
    for (int o = 32; o >= 1; o >>= 1) lm = fmaxf(lm, __shfl_xor(lm, o, 64));
    if (lane == 0) red[wave] = lm;
    __syncthreads();
    const float m = fmaxf(fmaxf(red[0], red[1]), fmaxf(red[2], red[3]));
    __syncthreads();

    float ev[8];
    float ls = 0.f;
    #pragma unroll
    for (int c = 0; c < 8; c++) {
        float e = (j0 + c < n) ? __expf(v[c] - m) : 0.f;
        ev[c] = e;
        ls += e;
    }
    #pragma unroll
    for (int o = 32; o >= 1; o >>= 1) ls += __shfl_xor(ls, o, 64);
    if (lane == 0) red[wave] = ls;
    __syncthreads();
    const float inv = 1.0f / (red[0] + red[1] + red[2] + red[3]);

    if (j0 < limit) {
        union { short8 s; unsigned short u[8]; } o;
        #pragma unroll
        for (int c = 0; c < 8; c++) o.u[c] = f2bf(ev[c] * inv);
        *(short8*)(row + j0) = o.s;
    }
}

__global__ __launch_bounds__(256)
void fill_zero(void* o, long n, const int* dtf)
{
    long i = (long)blockIdx.x * 256 + threadIdx.x;
    if (i < n) {
        if (*dtf) ((float*)o)[i] = 0.f;
        else ((unsigned short*)o)[i] = 0;
    }
}

extern "C" void kernel_launch(void* const* d_in, const int* in_sizes, int n_in,
                              void* d_out, int out_size, void* d_ws, size_t ws_size,
                              hipStream_t stream)
{
    const int B = 4, S = 2048, D = 1024;
    const void* x  = d_in[0];
    const void* Qw = d_in[1];
    const void* Kw = d_in[2];
    const void* Vw = d_in[3];
    (void)in_sizes; (void)n_in; (void)out_size;

    // scores = X (Qw Kw^T) X^T / 32 ; out = P (X Vw).
    //   prep -> WT = Kw@Qw^T/32 -> G = Xb@WT^T
    //   -> fused{Sc = G@Xb^T (causal, bf16), VbT = VwT@Xb^T}  [mode 5]
    //   -> softmax_b16 in place -> out = P@VbT^T  [mode 3]
    int* dtf = (int*)d_ws;
    char* p = (char*)d_ws + 4096;
    const size_t MB = (size_t)1 << 20;
    const unsigned short* nullB = nullptr;

    const long nOut = (long)B * S * D;
    const long nX = (long)B * S * D;
    const long nW = (long)D * D;
    const int prepBlocks = (int)(nX >> 11) + 2 * (int)(nW >> 11) + (D / 64) * (D / 64);

    // ---- Config A+: 88MB+4KB.
    // ws: dtf | QwB 2MB | KwB 2MB | Xb 16MB | Buf 16MB (G) | VbT 16MB |
    //     Sc bf16 32MB | WT 2MB | VwT 2MB (dedicated: VbT jobs read VwT
    //     concurrently with Sc writes in the mode-5 launch).
    const size_t needAp = 4096 + 88 * MB;
    if (ws_size >= needAp) {
        unsigned short* QwB = (unsigned short*)p;
        unsigned short* KwB = (unsigned short*)(p + 2 * MB);
        unsigned short* Xb  = (unsigned short*)(p + 4 * MB);
        unsigned short* Buf = (unsigned short*)(p + 20 * MB);
        unsigned short* VbT = (unsigned short*)(p + 36 * MB);
        unsigned short* Sc  = (unsigned short*)(p + 52 * MB);
        unsigned short* WT  = (unsigned short*)(p + 84 * MB);
        unsigned short* VwT = (unsigned short*)(p + 86 * MB);

        prep<<<dim3(prepBlocks), 256, 0, stream>>>(
            x, Qw, Kw, Vw, Xb, QwB, KwB, VwT, nX, nW, D, dtf);
        // WT = Kw @ Qw^T / 32   [256 blocks]
        gemm_bt<64><<<dim3(16, 16, 1), 256, 0, stream>>>(
            KwB, QwB, WT, D, D, D, D, 0L, 0L, 0L, 0L, 0L, 0L,
            0.03125f, 0, 0, dtf, 0, nullB, nullptr, nullB, 0);
        // G = Xb @ WT^T -> Buf   [512 blocks, 1 full round]
        gemm_bt<128><<<dim3(8, 64, 1), 256, 0, stream>>>(
            Xb, WT, Buf, D, D, D, D, 0L, 0L, 0L, 0L, 0L, 0L,
            1.0f, 0, 0, dtf, 0, nullB, nullptr, nullB, 0);
        // fused: Sc = G@Xb^T (causal, bf16) | VbT = VwT@Xb^T   [1056 blocks]
        gemm_bt<128><<<dim3(1056, 1, 1), 256, 0, stream>>>(
            Buf, Xb, Sc, D, D, D, S,
            0L, 0L, 0L, (long)S * D, (long)S * D, (long)S * S,
            1.0f, 5, 0, dtf, 0, nullB, VbT, VwT, S);
        softmax_causal_b16<<<dim3(S, 4), 256, 0, stream>>>(Sc, S, S, 0);
        // out = P @ VbT^T (mode 3, distance-256 balance)   [512 blocks]
        gemm_bt<128><<<dim3(512, 1, 1), 256, 0, stream>>>(
            Sc, VbT, d_out, S, S, S, D,
            0L, 0L, 0L, (long)S * S, (long)D * S, (long)S * D,
            1.0f, 3, 0, dtf, 2, nullB, nullptr, nullB, 0);
        return;
    }

    // ---- Config A: r11 structure (100MB+4KB) — z-form dual + xpose + fp32 Sc.
    const size_t needA = 4096 + 36 * MB + (size_t)B * S * S * 4;
    if (ws_size >= needA) {
        unsigned short* QwB = (unsigned short*)p;
        unsigned short* KwB = (unsigned short*)(p + 2 * MB);
        unsigned short* Xb  = (unsigned short*)(p + 4 * MB);
        unsigned short* Buf = (unsigned short*)(p + 20 * MB);
        float* Sc = (float*)(p + 36 * MB);
        unsigned short* WT  = (unsigned short*)Sc;            // Sc head
        unsigned short* VwT = (unsigned short*)((char*)Sc + 2 * MB);
        unsigned short* VbT = Xb;                             // Xb dead after Sc
        unsigned short* VbS = (unsigned short*)d_out;         // Vb scratch

        prep<<<dim3(prepBlocks), 256, 0, stream>>>(
            x, Qw, Kw, Vw, Xb, QwB, KwB, VwT, nX, nW, D, dtf);
        gemm_bt<64><<<dim3(16, 16, 1), 256, 0, stream>>>(
            KwB, QwB, WT, D, D, D, D, 0L, 0L, 0L, 0L, 0L, 0L,
            0.03125f, 0, 0, dtf, 0, nullB, nullptr, nullB, 0);
        gemm_bt<128><<<dim3(8, 64, 2), 256, 0, stream>>>(
            Xb, WT, Buf, D, D, D, D, 0L, 0L, 0L, 0L, 0L, 0L,
            1.0f, 0, 0, dtf, 0, VwT, VbS, nullB, 0);
        gemm_bt<128><<<dim3(136, 1, 4), 256, 0, stream>>>(
            Buf, Xb, (void*)Sc, D, D, D, S,
            0L, 0L, 0L, (long)S * D, (long)S * D, (long)S * S,
            1.0f, 1, 0, dtf, 1, nullB, nullptr, nullB, 0);
        softmax_causal<<<dim3(S, 4), 256, 0, stream>>>(Sc, S, S, 0);
        xpose_cast<<<dim3(16, 32, 4), 256, 0, stream>>>(
            VbS, VbT, nullptr, S, D, 0L, (long)S * D, (long)D * S, 0L, dtf, 0);
        gemm_bt<128><<<dim3(512, 1, 1), 256, 0, stream>>>(
            (const unsigned short*)Sc, VbT, d_out, S, 2 * S, S, D,
            0L, 0L, 0L, (long)2 * S * S, (long)D * S, (long)S * D,
            1.0f, 3, 0, dtf, 2, nullB, nullptr, nullB, 0);
        return;
    }

    // ---- Generic chunked fallback: fixed = 56MB + Sc chunk (fp32).
    const int cfgs[6][2] = {{4,1024},{2,1024},{1,1024},{1,512},{1,256},{1,128}};
    int ZB = 0, CH = 0;
    for (int i = 0; i < 6; i++) {
        size_t need = 4096 + 56 * MB + (size_t)cfgs[i][0] * cfgs[i][1] * S * 4;
        if (need <= ws_size) { ZB = cfgs[i][0]; CH = cfgs[i][1]; break; }
    }
    if (ZB == 0) {  // diagnostic zeros
        detect_dtype<<<1, 256, 0, stream>>>((const unsigned short*)x, dtf);
        fill_zero<<<dim3((unsigned)((nOut + 255) / 256)), 256, 0, stream>>>(d_out, nOut, dtf);
        return;
    }

    unsigned short* QwB = (unsigned short*)p;
    unsigned short* KwB = (unsigned short*)(p + 2 * MB);
    unsigned short* WT  = (unsigned short*)(p + 4 * MB);
    unsigned short* VwT = (unsigned short*)(p + 6 * MB);
    unsigned short* Xb  = (unsigned short*)(p + 8 * MB);
    unsigned short* VbT = (unsigned short*)(p + 24 * MB);
    unsigned short* Buf = (unsigned short*)(p + 40 * MB);
    float* Sc = (float*)(p + 56 * MB);
    unsigned short* VbS = (unsigned short*)d_out;   // Vb scratch (dead pre-out)

    prep<<<dim3(prepBlocks), 256, 0, stream>>>(
        x, Qw, Kw, Vw, Xb, QwB, KwB, VwT, nX, nW, D, dtf);
    gemm_bt<64><<<dim3(16, 16, 1), 256, 0, stream>>>(
        KwB, QwB, WT, D, D, D, D, 0L, 0L, 0L, 0L, 0L, 0L,
        0.03125f, 0, 0, dtf, 0, nullB, nullptr, nullB, 0);
    gemm_bt<128><<<dim3(8, 64, 2), 256, 0, stream>>>(
        Xb, WT, Buf, D, D, D, D, 0L, 0L, 0L, 0L, 0L, 0L,
        1.0f, 0, 0, dtf, 0, VwT, VbS, nullB, 0);
    xpose_cast<<<dim3(16, 32, 4), 256, 0, stream>>>(
        VbS, VbT, nullptr, S, D, 0L, (long)S * D, (long)D * S, 0L, dtf, 0);

    for (int b0 = 0; b0 < B; b0 += ZB) {
        for (int q0 = 0; q0 < S; q0 += CH) {
            const int base = q0 / 128, R = CH / 128;
            const int ntiles = R * (base + 1) + R * (R - 1) / 2;

            gemm_bt<128><<<dim3(ntiles, 1, ZB), 256, 0, stream>>>(
                Buf, Xb, (void*)Sc, D, D, D, S,
                (long)b0 * S * D + (long)q0 * D, (long)b0 * S * D, 0L,
                (long)S * D, (long)S * D, (long)CH * S,
                1.0f, 1, q0, dtf, 1, nullB, nullptr, nullB, 0);

            softmax_causal<<<dim3(CH, ZB), 256, 0, stream>>>(Sc, S, CH, q0);

            gemm_bt<128><<<dim3(8, CH / 128, ZB), 256, 0, stream>>>(
                (const unsigned short*)Sc, VbT, d_out, S, 2 * S, S, D,
                0L, (long)b0 * D * S, (long)b0 * S * D + (long)q0 * D,
                (long)CH * 2 * S, (long)D * S, (long)S * D,
                1.0f, 2, q0, dtf, 2, nullB, nullptr, nullB, 0);
        }
    }
}